// Round 10
// baseline (818.108 us; speedup 1.0000x reference)
//
#include <hip/hip_runtime.h>
#include <stdint.h>

#define NN      50000
#define NN_PAD  50176   // 784 * 64
#define NE      800000
#define INCH    8
#define CH      128
#define EA      6
#define NB      2000
#define NB_PAD  2048
#define NCLS    32
#define FUS     384
#define K1      2816   // 1408 + 1024 + 384
#define SCAN_NBLK 49   // (NN + 1023) / 1024

typedef _Float16 half8 __attribute__((ext_vector_type(8)));
typedef _Float16 h2 __attribute__((ext_vector_type(2)));
typedef float f32x4 __attribute__((ext_vector_type(4)));

// ---------- degree of dst nodes ----------
__global__ __launch_bounds__(256) void k_deg(const int* __restrict__ edge,
                                             int* __restrict__ deg) {
  int e = blockIdx.x * 256 + threadIdx.x;
  if (e < NE) atomicAdd(&deg[edge[NE + e]], 1);
}

// ---------- parallel scan, phase 1: per-block inclusive scan + block sums ----
__global__ __launch_bounds__(1024) void k_scan1(const int* __restrict__ deg,
                                                int* __restrict__ row_ptr,
                                                int* __restrict__ bsum) {
  __shared__ int wsum[16];
  const int t = threadIdx.x, lane = t & 63, w = t >> 6;
  const int i = blockIdx.x * 1024 + t;
  int x = (i < NN) ? deg[i] : 0;
#pragma unroll
  for (int off = 1; off < 64; off <<= 1) {
    int y = __shfl_up(x, off, 64);
    if (lane >= off) x += y;
  }
  if (lane == 63) wsum[w] = x;
  __syncthreads();
  if (w == 0 && lane < 16) {
    int s = wsum[lane];
#pragma unroll
    for (int off = 1; off < 16; off <<= 1) {
      int y = __shfl_up(s, off, 64);
      if (lane >= off) s += y;
    }
    wsum[lane] = s;
  }
  __syncthreads();
  int incl = x + ((w == 0) ? 0 : wsum[w - 1]);
  if (i < NN) row_ptr[i + 1] = incl;
  if (t == 1023) bsum[blockIdx.x] = incl;
}

// ---------- phase 2: single-wave exclusive scan of block sums ----------
__global__ __launch_bounds__(64) void k_scan2(int* __restrict__ bsum) {
  const int t = threadIdx.x;
  int x = (t < SCAN_NBLK) ? bsum[t] : 0;
#pragma unroll
  for (int off = 1; off < 64; off <<= 1) {
    int y = __shfl_up(x, off, 64);
    if (t >= off) x += y;
  }
  int ex = __shfl_up(x, 1, 64);
  if (t == 0) ex = 0;
  if (t < SCAN_NBLK) bsum[t] = ex;
}

// ---------- phase 3: add block offsets ----------
__global__ __launch_bounds__(256) void k_scan3(const int* __restrict__ bsum,
                                               int* __restrict__ row_ptr) {
  const int i = blockIdx.x * 256 + threadIdx.x;
  if (i == 0) row_ptr[0] = 0;
  if (i < NN) row_ptr[i + 1] += bsum[i >> 10];
}

// ---------- fill CSR payload: dst-sorted src + f16 e_attr ----------
__global__ __launch_bounds__(256) void k_fill(
    const int* __restrict__ edge, const float* __restrict__ eattr,
    const int* __restrict__ row_ptr, int* __restrict__ cursor,
    int* __restrict__ ssrc, _Float16* __restrict__ sea8) {
  int e = blockIdx.x * 256 + threadIdx.x;
  if (e >= NE) return;
  int s = edge[e], d = edge[NE + e];
  int idx = row_ptr[d] + atomicAdd(&cursor[d], 1);
  ssrc[idx] = s;
  half8 v;
#pragma unroll
  for (int j = 0; j < EA; ++j) v[j] = (_Float16)eattr[(size_t)e * EA + j];
  v[6] = (_Float16)0.f; v[7] = (_Float16)0.f;
  *(half8*)(sea8 + (size_t)idx * 8) = v;
}

// ---------- segment starts from sorted bbox_idx ----------
__global__ __launch_bounds__(256) void k_segstart(const int* __restrict__ bbox,
                                                  int* __restrict__ seg) {
  int i = blockIdx.x * 256 + threadIdx.x;
  if (i >= NN) return;
  int bc = bbox[i];
  int bp = (i == 0) ? -1 : bbox[i - 1];
  for (int j = bp + 1; j <= bc; ++j) seg[j] = i;
  if (i == NN - 1)
    for (int j = bc + 1; j <= NB; ++j) seg[j] = NN;
}

// ---------- head node transform (K=8), both streams via blockIdx.y ----------
__global__ __launch_bounds__(256) void k_node_pq(
    const float* __restrict__ X, int ldx, int K,
    const float* __restrict__ WN, const float* __restrict__ bN,
    const float* __restrict__ WS, const float* __restrict__ bS,
    _Float16* __restrict__ PQi, _Float16* __restrict__ Qi) {
  const int sel = blockIdx.y;
  const float* W = sel ? WS : WN;
  const float* bias = sel ? bS : bN;
  const int t = threadIdx.x, lane = t & 63, wv = t >> 6;
  const int nbase = blockIdx.x * 32 + wv * 8;
  const int c = lane * 2;
  const float2 bv = *(const float2*)(bias + c);
  float2 pacc[8], qacc[8];
#pragma unroll
  for (int u = 0; u < 8; ++u) { pacc[u] = bv; qacc[u] = make_float2(0.f, 0.f); }
  const int xrow = min(nbase + (lane >> 3), NN - 1);
  const int xk = lane & 7;
  for (int k0 = 0; k0 < K; k0 += 8) {
    const float xv = X[(size_t)xrow * ldx + k0 + xk];
#pragma unroll
    for (int j = 0; j < 8; ++j) {
      const float2 w1 = *(const float2*)(W + (size_t)(k0 + j) * CH + c);
      const float2 w2 = *(const float2*)(W + (size_t)(K + k0 + j) * CH + c);
      const float2 wd = {w1.x - w2.x, w1.y - w2.y};
#pragma unroll
      for (int u = 0; u < 8; ++u) {
        const float xs = __shfl(xv, u * 8 + j, 64);
        pacc[u].x += xs * wd.x; pacc[u].y += xs * wd.y;
        qacc[u].x += xs * w2.x; qacc[u].y += xs * w2.y;
      }
    }
  }
#pragma unroll
  for (int u = 0; u < 8; ++u) {
    const int node = nbase + u;
    if (node < NN) {
      const size_t o = ((size_t)node * 64 + lane) * 4 + sel * 2;
      *(h2*)(PQi + o) = (h2){(_Float16)pacc[u].x, (_Float16)pacc[u].y};
      *(h2*)(Qi + o)  = (h2){(_Float16)qacc[u].x, (_Float16)qacc[u].y};
    }
  }
}

// ---------- pack [W1-W2 | W2] into f16 B-frags, both res-blocks (z) ----------
__global__ __launch_bounds__(64) void k_cvtWnpq(
    const float* __restrict__ WbAll, const float* __restrict__ WbsAll,
    _Float16* __restrict__ whN, _Float16* __restrict__ whS) {
  const int blk = blockIdx.z;
  const float* W = (blockIdx.y ? WbsAll : WbAll) + (size_t)blk * 262 * CH;
  _Float16* wh   = (blockIdx.y ? whS : whN) + (size_t)blk * 32768;
  const int c = blockIdx.x >> 4, tile = blockIdx.x & 15;
  const int L = threadIdx.x;
  const int n = tile * 16 + (L & 15);
  const int k0 = c * 32 + (L >> 4) * 8;
  half8 v;
#pragma unroll
  for (int j = 0; j < 8; ++j) {
    const int k = k0 + j;
    float val;
    if (n < CH) val = W[(size_t)k * CH + n] - W[(size_t)(CH + k) * CH + n];
    else        val = W[(size_t)(CH + k) * CH + (n - CH)];
    v[j] = (_Float16)val;
  }
  *(half8*)(wh + (((size_t)(c * 16 + tile)) * 64 + L) * 8) = v;
}

// ---------- residual node transform on matrix cores (both streams) ----------
// R7: X is f16 row-major [node][FUS] -> direct half8 A loads, no cvts.
__global__ __launch_bounds__(256) void k_npq_mfma(
    const _Float16* __restrict__ Xn, const _Float16* __restrict__ Xs, int ldx,
    const _Float16* __restrict__ whN, const _Float16* __restrict__ whS,
    const float* __restrict__ biasN, const float* __restrict__ biasS,
    _Float16* __restrict__ PQi, _Float16* __restrict__ Qi) {
  const int sel = blockIdx.y;
  const _Float16* X = sel ? Xs : Xn;
  const _Float16* wh = sel ? whS : whN;
  const float* bias = sel ? biasS : biasN;
  const int t = threadIdx.x, lane = t & 63, wv = t >> 6;
  const int nbase = blockIdx.x * 64;
  const int m = lane & 15, quad = lane >> 4;
  f32x4 acc[4][4];
#pragma unroll
  for (int i = 0; i < 4; ++i)
#pragma unroll
    for (int nt = 0; nt < 4; ++nt) acc[i][nt] = (f32x4){0.f, 0.f, 0.f, 0.f};
#pragma unroll
  for (int ks = 0; ks < 4; ++ks) {
    half8 b[4];
#pragma unroll
    for (int nt = 0; nt < 4; ++nt)
      b[nt] = *(const half8*)(wh + (((size_t)(ks * 16 + wv * 4 + nt)) * 64 + lane) * 8);
#pragma unroll
    for (int i = 0; i < 4; ++i) {
      const int row = min(nbase + i * 16 + m, NN - 1);
      const half8 a = *(const half8*)(X + (size_t)row * ldx + ks * 32 + quad * 8);
#pragma unroll
      for (int nt = 0; nt < 4; ++nt)
        acc[i][nt] = __builtin_amdgcn_mfma_f32_16x16x32_f16(a, b[nt], acc[i][nt],
                                                            0, 0, 0);
    }
  }
#pragma unroll
  for (int i = 0; i < 4; ++i)
#pragma unroll
    for (int nt = 0; nt < 4; ++nt) {
      const int col = wv * 64 + nt * 16 + m;
      const float bv = (col < CH) ? bias[col] : 0.f;
#pragma unroll
      for (int r = 0; r < 4; ++r) {
        const int row = nbase + i * 16 + quad * 4 + r;
        if (row < NN) {
          const float v = acc[i][nt][r] + bv;
          if (col < CH)
            PQi[((size_t)row * 64 + (col >> 1)) * 4 + sel * 2 + (col & 1)] =
                (_Float16)v;
          else {
            const int qc = col - CH;
            Qi[((size_t)row * 64 + (qc >> 1)) * 4 + sel * 2 + (qc & 1)] =
                (_Float16)v;
          }
        }
      }
    }
}

// ---------- fused dual-stream CSR conv ----------
// R2: packed-f16 edge math + gather prefetch. R7: f16 feats + 8-deep gathers.
__global__ __launch_bounds__(256) void k_conv2(
    const int* __restrict__ row_ptr, const int* __restrict__ ssrc,
    const _Float16* __restrict__ sea8,
    const _Float16* __restrict__ PQi, const _Float16* __restrict__ Qi,
    const float* __restrict__ Cn, const float* __restrict__ Cs,
    _Float16* __restrict__ feats, _Float16* __restrict__ sfeats,
    int cur, int prev) {
  const int t = threadIdx.x;
  const int lane = t & 63;
  const int node = blockIdx.x * 4 + (t >> 6);
  const int c = lane * 2;
  h2 cwnh[EA], cwsh[EA];
#pragma unroll
  for (int j = 0; j < EA; ++j) {
    const float2 a = *(const float2*)(Cn + j * CH + c);
    const float2 b = *(const float2*)(Cs + j * CH + c);
    cwnh[j] = (h2){(_Float16)a.x, (_Float16)a.y};
    cwsh[j] = (h2){(_Float16)b.x, (_Float16)b.y};
  }
  int i0 = __builtin_amdgcn_readfirstlane(row_ptr[node]);
  int i1 = __builtin_amdgcn_readfirstlane(row_ptr[node + 1]);
  const uint2 qv = *(const uint2*)(Qi + ((size_t)node * 64 + lane) * 4);
  const h2 qnh = *(const h2*)&qv.x;
  const h2 qsh = *(const h2*)&qv.y;
  const _Float16* pqL = PQi + (size_t)lane * 4;  // + s*256 per edge
  h2 anh = (h2){(_Float16)0.f, (_Float16)0.f};
  float as0 = 0.f, as1 = 0.f;
  const h2 zero = (h2){(_Float16)0.f, (_Float16)0.f};
#define COMP(PV, J)                                                        \
  {                                                                        \
    unsigned w0 = __shfl((int)ea_l.x, (J), 64);                            \
    unsigned w1 = __shfl((int)ea_l.y, (J), 64);                            \
    unsigned w2 = __shfl((int)ea_l.z, (J), 64);                            \
    const h2 ea01 = *(const h2*)&w0;                                       \
    const h2 ea23 = *(const h2*)&w1;                                       \
    const h2 ea45 = *(const h2*)&w2;                                       \
    h2 vn = *(const h2*)&PV.x + qnh;                                       \
    h2 vs = *(const h2*)&PV.y + qsh;                                       \
    h2 b;                                                                  \
    b = (h2){ea01[0], ea01[0]}; vn += b * cwnh[0]; vs += b * cwsh[0];      \
    b = (h2){ea01[1], ea01[1]}; vn += b * cwnh[1]; vs += b * cwsh[1];      \
    b = (h2){ea23[0], ea23[0]}; vn += b * cwnh[2]; vs += b * cwsh[2];      \
    b = (h2){ea23[1], ea23[1]}; vn += b * cwnh[3]; vs += b * cwsh[3];      \
    b = (h2){ea45[0], ea45[0]}; vn += b * cwnh[4]; vs += b * cwsh[4];      \
    b = (h2){ea45[1], ea45[1]}; vn += b * cwnh[5]; vs += b * cwsh[5];      \
    anh = __builtin_elementwise_max(anh, vn);                              \
    const h2 vsr = __builtin_elementwise_max(vs, zero);                    \
    as0 += (float)vsr[0]; as1 += (float)vsr[1];                            \
  }
  for (int base = i0; base < i1; base += 64) {
    const int cnt = min(64, i1 - base);
    int s_l = 0;
    uint4 ea_l = {0u, 0u, 0u, 0u};
    if (lane < cnt) {
      s_l = ssrc[base + lane];
      ea_l = *(const uint4*)(sea8 + (size_t)(base + lane) * 8);
    }
    int j = 0;
    for (; j + 8 <= cnt; j += 8) {
      // 8 independent row gathers in flight before any compute
      const int s0 = __shfl(s_l, j, 64),     s1 = __shfl(s_l, j + 1, 64);
      const int s2 = __shfl(s_l, j + 2, 64), s3 = __shfl(s_l, j + 3, 64);
      const int s4 = __shfl(s_l, j + 4, 64), s5 = __shfl(s_l, j + 5, 64);
      const int s6 = __shfl(s_l, j + 6, 64), s7 = __shfl(s_l, j + 7, 64);
      const uint2 p0 = *(const uint2*)(pqL + (size_t)s0 * 256);
      const uint2 p1 = *(const uint2*)(pqL + (size_t)s1 * 256);
      const uint2 p2 = *(const uint2*)(pqL + (size_t)s2 * 256);
      const uint2 p3 = *(const uint2*)(pqL + (size_t)s3 * 256);
      const uint2 p4 = *(const uint2*)(pqL + (size_t)s4 * 256);
      const uint2 p5 = *(const uint2*)(pqL + (size_t)s5 * 256);
      const uint2 p6 = *(const uint2*)(pqL + (size_t)s6 * 256);
      const uint2 p7 = *(const uint2*)(pqL + (size_t)s7 * 256);
      COMP(p0, j)     COMP(p1, j + 1) COMP(p2, j + 2) COMP(p3, j + 3)
      COMP(p4, j + 4) COMP(p5, j + 5) COMP(p6, j + 6) COMP(p7, j + 7)
    }
    for (; j + 4 <= cnt; j += 4) {
      const int s0 = __shfl(s_l, j, 64),     s1 = __shfl(s_l, j + 1, 64);
      const int s2 = __shfl(s_l, j + 2, 64), s3 = __shfl(s_l, j + 3, 64);
      const uint2 p0 = *(const uint2*)(pqL + (size_t)s0 * 256);
      const uint2 p1 = *(const uint2*)(pqL + (size_t)s1 * 256);
      const uint2 p2 = *(const uint2*)(pqL + (size_t)s2 * 256);
      const uint2 p3 = *(const uint2*)(pqL + (size_t)s3 * 256);
      COMP(p0, j) COMP(p1, j + 1) COMP(p2, j + 2) COMP(p3, j + 3)
    }
    for (; j < cnt; ++j) {
      const int s0 = __shfl(s_l, j, 64);
      const uint2 p0 = *(const uint2*)(pqL + (size_t)s0 * 256);
      COMP(p0, j)
    }
  }
#undef COMP
  float an0 = (float)anh[0], an1 = (float)anh[1];
  const float inv = 1.f / fmaxf((float)(i1 - i0), 1.f);
  as0 *= inv; as1 *= inv;
  const size_t o = (size_t)node * FUS + (size_t)cur * CH + c;
  if (prev >= 0) {
    const size_t op = (size_t)node * FUS + (size_t)prev * CH + c;
    const h2 prn = *(const h2*)(feats + op);
    const h2 prs = *(const h2*)(sfeats + op);
    an0 += (float)prn[0]; an1 += (float)prn[1];
    as0 += (float)prs[0]; as1 += (float)prs[1];
  }
  *(h2*)(feats + o)  = (h2){(_Float16)an0, (_Float16)an1};
  *(h2*)(sfeats + o) = (h2){(_Float16)as0, (_Float16)as1};
}

// ---------- convert + pack W (KxN f32) into f16 B-fragment order ----------
template <int N, int NT>
__global__ __launch_bounds__(64) void k_cvtB(const float* __restrict__ W,
                                             _Float16* __restrict__ wh) {
  const int c = blockIdx.x / NT;
  const int tile = blockIdx.x % NT;
  const int L = threadIdx.x;
  const int n = tile * 16 + (L & 15);
  const int k0 = c * 32 + (L >> 4) * 8;
  half8 v;
#pragma unroll
  for (int j = 0; j < 8; ++j) v[j] = (_Float16)W[(size_t)(k0 + j) * N + n];
  *(half8*)(wh + (((size_t)(c * NT + tile)) * 64 + L) * 8) = v;
}

// ---------- dual-source variant (merged launch for W_f / W_fs) ----------
template <int N, int NT>
__global__ __launch_bounds__(64) void k_cvtB2(const float* __restrict__ WA,
                                              const float* __restrict__ WB,
                                              _Float16* __restrict__ whA,
                                              _Float16* __restrict__ whB) {
  const float* W = blockIdx.y ? WB : WA;
  _Float16* wh   = blockIdx.y ? whB : whA;
  const int c = blockIdx.x / NT;
  const int tile = blockIdx.x % NT;
  const int L = threadIdx.x;
  const int n = tile * 16 + (L & 15);
  const int k0 = c * 32 + (L >> 4) * 8;
  half8 v;
#pragma unroll
  for (int j = 0; j < 8; ++j) v[j] = (_Float16)W[(size_t)(k0 + j) * N + n];
  *(half8*)(wh + (((size_t)(c * NT + tile)) * 64 + L) * 8) = v;
}

// ---------- fusion GEMM + segment max ----
// R0: cg fastest within XCD. R1: two-phase epilogue. R8: phase-carry runs.
// R9: BARRIER-FREE K-loop. The 12 per-ks __syncthreads each forced
// s_waitcnt vmcnt(0) (barrier semantics drain ALL global loads), so every
// ks paid a full L2 round-trip that 6 blocks/CU could not hide -- the gap
// between the 19us MFMA / 26us L2 floors and the measured 75us (occupancy,
// ILP, LDS-dedup, atomics all tested neutral). New wave partition: 2x2
// rows-x-cols -- wave wv owns rows (wv>>1)*32..+31, cols (wv&1)*64..+63,
// needing only its own 2 A-frags + 4 B-frags per ks: no LDS staging, ZERO
// K-loop barriers, waves free-run. Duplicate A/B readers hit L1 (16KB/ks
// B-set << 32KB L1), so effective L2 traffic stays ~144KB/block. Same
// MFMA count + accumulation order -> bit-identical output.
__global__ __launch_bounds__(256, 6) void k_pool_mfma(
    const _Float16* __restrict__ feats16, const _Float16* __restrict__ wh,
    const int* __restrict__ bbox, const float* __restrict__ bf,
    float* __restrict__ pooled) {
  __shared__ float cl[32 * 132];
  __shared__ int s_bb[64];
  const int t = threadIdx.x, lane = t & 63, wv = t >> 6;
  const int fid = blockIdx.x;
  const int xcd = fid & 7, slot = fid >> 3;
  const int cg = slot & 7;
  const int rb = xcd * 98 + (slot >> 3);
  const int nbase = rb * 64;
  const int m = lane & 15, quad = lane >> 4;
  if (t < 64) s_bb[t] = bbox[min(nbase + t, NN - 1)];
  const int rg = wv >> 1, ch = wv & 1;   // row-group, col-half
  f32x4 acc[2][4];
#pragma unroll
  for (int i = 0; i < 2; ++i)
#pragma unroll
    for (int nt = 0; nt < 4; ++nt) acc[i][nt] = (f32x4){0.f, 0.f, 0.f, 0.f};
  // A: rows nbase + rg*32 + i*16 + m (i=0,1), cols ks*32 + quad*8
  const _Float16* ap = feats16 + (size_t)(nbase + rg * 32 + m) * FUS + quad * 8;
  // B: tiles cg*8 + ch*4 + nt (nt=0..3), tile stride 512 halves
  const _Float16* bp = wh + ((size_t)(cg * 8 + ch * 4) * 64 + lane) * 8;
#pragma unroll
  for (int ks = 0; ks < 12; ++ks) {
    half8 b[4], a[2];
#pragma unroll
    for (int nt = 0; nt < 4; ++nt)
      b[nt] = *(const half8*)(bp + (size_t)ks * 32768 + nt * 512);
#pragma unroll
    for (int i = 0; i < 2; ++i)
      a[i] = *(const half8*)(ap + (size_t)(i * 16) * FUS + ks * 32);
#pragma unroll
    for (int i = 0; i < 2; ++i)
#pragma unroll
      for (int nt = 0; nt < 4; ++nt)
        acc[i][nt] = __builtin_amdgcn_mfma_f32_16x16x32_f16(a[i], b[nt],
                                                            acc[i][nt], 0, 0, 0);
  }
  // epilogue: phase p spills acc[p][*] -> cl holds global rows
  // {p*16+0..15 (rg=0), 32+p*16+0..15 (rg=1)}; thread span stays the
  // contiguous g = rh*32 + p*16 + rr (R8 phase-carry run merge).
  const int col = t & 127, rh = t >> 7;
  const int gcol = cg * 128 + col;
  const float bias = bf[gcol];
  int curb = -1;
  float mx = 0.f;
#pragma unroll
  for (int p = 0; p < 2; ++p) {
    __syncthreads();  // p=0: orders s_bb; p=1: phase-0 readers done with cl
#pragma unroll
    for (int nt = 0; nt < 4; ++nt) {
      const int scol = ch * 64 + nt * 16 + m;
#pragma unroll
      for (int r = 0; r < 4; ++r)
        cl[(rg * 16 + quad * 4 + r) * 132 + scol] = acc[p][nt][r];
    }
    __syncthreads();
    for (int rr = 0; rr < 16; ++rr) {
      const int g = rh * 32 + p * 16 + rr;   // contiguous per-thread span
      const int node = nbase + g;
      if (node >= NN) break;
      const int bid = s_bb[g];
      const float v = fmaxf(cl[(rh * 16 + rr) * 132 + col] + bias, 0.f);
      if (bid != curb) {
        if (curb >= 0)
          atomicMax((unsigned*)(pooled + (size_t)curb * 1408 + gcol),
                    __float_as_uint(mx));
        curb = bid;
        mx = v;
      } else {
        mx = fmaxf(mx, v);
      }
    }
  }
  if (curb >= 0)
    atomicMax((unsigned*)(pooled + (size_t)curb * 1408 + gcol),
              __float_as_uint(mx));
}

// ---------- raw-feats bbox max + sfeats bbox mean (+ f16 sb copy) ----------
__global__ __launch_bounds__(256) void k_poolraw(
    const _Float16* __restrict__ feats, const _Float16* __restrict__ sfeats,
    const int* __restrict__ seg, float* __restrict__ pooled,
    float* __restrict__ sb, _Float16* __restrict__ sbH) {
  const int b = blockIdx.x, t = threadIdx.x;
  if (t >= 192) return;
  const int c2 = t * 2;
  const int n0 = __builtin_amdgcn_readfirstlane(seg[b]);
  const int n1 = __builtin_amdgcn_readfirstlane(seg[b + 1]);
  float2 fmx = {0.f, 0.f}, ss = {0.f, 0.f};
  for (int n = n0; n < n1; ++n) {
    const h2 f2 = *(const h2*)(feats + (size_t)n * FUS + c2);
    fmx.x = fmaxf(fmx.x, (float)f2[0]); fmx.y = fmaxf(fmx.y, (float)f2[1]);
    const h2 s2 = *(const h2*)(sfeats + (size_t)n * FUS + c2);
    ss.x += (float)s2[0]; ss.y += (float)s2[1];
  }
  *(float2*)(pooled + (size_t)b * 1408 + 1024 + c2) = fmx;
  const float inv = 1.f / fmaxf((float)(n1 - n0), 1.f);
  float2 o = {ss.x * inv, ss.y * inv};
  *(float2*)(sb + (size_t)b * FUS + c2) = o;
  *(h2*)(sbH + (size_t)b * FUS + c2) = (h2){(_Float16)o.x, (_Float16)o.y};
}

// ---------- fusion_super = relu(sbH @ WfsH + bfs) on matrix cores ----------
__global__ __launch_bounds__(256) void k_fsup_mfma(
    const _Float16* __restrict__ sbH, const _Float16* __restrict__ wh,
    const float* __restrict__ bfs, float* __restrict__ fs) {
  const int t = threadIdx.x, lane = t & 63, wv = t >> 6;
  const int nbase = blockIdx.x * 64;
  const int cg = blockIdx.y;
  const int m = lane & 15, quad = lane >> 4;
  f32x4 acc[4][2];
#pragma unroll
  for (int i = 0; i < 4; ++i)
#pragma unroll
    for (int nt = 0; nt < 2; ++nt) acc[i][nt] = (f32x4){0.f, 0.f, 0.f, 0.f};
  const _Float16* ap = sbH + (size_t)(nbase + m) * FUS + quad * 8;
  const _Float16* bp = wh + ((size_t)(cg * 8 + wv * 2) * 64 + lane) * 8;
#pragma unroll
  for (int ks = 0; ks < 12; ++ks) {
    const half8 b0 = *(const half8*)(bp + (size_t)ks * 32768);
    const half8 b1v = *(const half8*)(bp + (size_t)ks * 32768 + 512);
#pragma unroll
    for (int i = 0; i < 4; ++i) {
      const half8 a = *(const half8*)(ap + (size_t)(i * 16) * FUS + ks * 32);
      acc[i][0] = __builtin_amdgcn_mfma_f32_16x16x32_f16(a, b0, acc[i][0], 0, 0, 0);
      acc[i][1] = __builtin_amdgcn_mfma_f32_16x16x32_f16(a, b1v, acc[i][1], 0, 0, 0);
    }
  }
#pragma unroll
  for (int i = 0; i < 4; ++i)
#pragma unroll
    for (int nt = 0; nt < 2; ++nt) {
      const int gcol = cg * 128 + wv * 32 + nt * 16 + m;
      const float bias = bfs[gcol];
#pragma unroll
      for (int r = 0; r < 4; ++r) {
        const int row = nbase + i * 16 + quad * 4 + r;
        if (row < NB)
          fs[(size_t)row * 1024 + gcol] = fmaxf(acc[i][nt][r] + bias, 0.f);
      }
    }
}

// ---------- concat [pooled | fsup | sb] -> f16 bbH[NB_PAD][K1], zero-padded ----
__global__ __launch_bounds__(256) void k_cvt_cat(
    const float* __restrict__ pooled, const float* __restrict__ fsup,
    const float* __restrict__ sb, _Float16* __restrict__ bbH) {
  const size_t off = ((size_t)blockIdx.x * 256 + threadIdx.x) * 8;
  const int row = (int)(off / K1);
  const int col = (int)(off - (size_t)row * K1);
  half8 v;
  if (row < NB) {
    const float* src;
    if (col < 1408)      src = pooled + (size_t)row * 1408 + col;
    else if (col < 2432) src = fsup + (size_t)row * 1024 + (col - 1408);
    else                 src = sb + (size_t)row * FUS + (col - 2432);
    const float4 f0 = *(const float4*)src;
    const float4 f1 = *(const float4*)(src + 4);
    v[0] = (_Float16)f0.x; v[1] = (_Float16)f0.y;
    v[2] = (_Float16)f0.z; v[3] = (_Float16)f0.w;
    v[4] = (_Float16)f1.x; v[5] = (_Float16)f1.y;
    v[6] = (_Float16)f1.z; v[7] = (_Float16)f1.w;
  } else {
#pragma unroll
    for (int j = 0; j < 8; ++j) v[j] = (_Float16)0.f;
  }
  *(half8*)(bbH + off) = v;
}

// ---------- h1 = relu(bbH @ W1 + b1) on matrix cores ----------
__global__ __launch_bounds__(256) void k_mlp1_mfma(
    const _Float16* __restrict__ bbH, const _Float16* __restrict__ wh,
    const float* __restrict__ b1, float* __restrict__ h1) {
  const int t = threadIdx.x, lane = t & 63, wv = t >> 6;
  const int nbase = blockIdx.x * 64;
  const int cg = blockIdx.y;
  const int m = lane & 15, quad = lane >> 4;
  f32x4 acc[4][2];
#pragma unroll
  for (int i = 0; i < 4; ++i)
#pragma unroll
    for (int nt = 0; nt < 2; ++nt) acc[i][nt] = (f32x4){0.f, 0.f, 0.f, 0.f};
  const _Float16* ap = bbH + (size_t)(nbase + m) * K1 + quad * 8;
  const _Float16* bp = wh + ((size_t)(cg * 8 + wv * 2) * 64 + lane) * 8;
#pragma unroll 4
  for (int ks = 0; ks < 88; ++ks) {
    const half8 b0 = *(const half8*)(bp + (size_t)ks * 16384);
    const half8 b1v = *(const half8*)(bp + (size_t)ks * 16384 + 512);
#pragma unroll
    for (int i = 0; i < 4; ++i) {
      const half8 a = *(const half8*)(ap + (size_t)(i * 16) * K1 + ks * 32);
      acc[i][0] = __builtin_amdgcn_mfma_f32_16x16x32_f16(a, b0, acc[i][0], 0, 0, 0);
      acc[i][1] = __builtin_amdgcn_mfma_f32_16x16x32_f16(a, b1v, acc[i][1], 0, 0, 0);
    }
  }
#pragma unroll
  for (int i = 0; i < 4; ++i)
#pragma unroll
    for (int nt = 0; nt < 2; ++nt) {
      const int gcol = cg * 128 + wv * 32 + nt * 16 + m;
      const float bias = b1[gcol];
#pragma unroll
      for (int r = 0; r < 4; ++r) {
        const int row = nbase + i * 16 + quad * 4 + r;
        if (row < NB)
          h1[(size_t)row * 512 + gcol] = fmaxf(acc[i][nt][r] + bias, 0.f);
      }
    }
}

// ---------- h2 = relu(h1 @ W2 + b2) ----------
__global__ __launch_bounds__(256) void k_mlp2(
    const float* __restrict__ h1, const float* __restrict__ W2,
    const float* __restrict__ b2, float* __restrict__ h2o) {
  const int r0 = blockIdx.x * 8, t = threadIdx.x;
  float acc[8];
#pragma unroll
  for (int u = 0; u < 8; ++u) acc[u] = 0.f;
  for (int k = 0; k < 512; ++k) {
    float w = W2[(size_t)k * 256 + t];
#pragma unroll
    for (int u = 0; u < 8; ++u) acc[u] += h1[(size_t)(r0 + u) * 512 + k] * w;
  }
  float bv = b2[t];
#pragma unroll
  for (int u = 0; u < 8; ++u)
    h2o[(size_t)(r0 + u) * 256 + t] = fmaxf(acc[u] + bv, 0.f);
}

// ---------- logits = h2 @ W3 + b3 ----------
__global__ __launch_bounds__(256) void k_mlp3(
    const float* __restrict__ h2i, const float* __restrict__ W3,
    const float* __restrict__ b3, float* __restrict__ out) {
  const int r0 = blockIdx.x * 8, t = threadIdx.x;
  const int u = t >> 5, oc = t & 31;
  const float* x = h2i + (size_t)(r0 + u) * 256;
  float acc = 0.f;
  for (int k = 0; k < 256; ++k) acc += x[k] * W3[(size_t)k * 32 + oc];
  out[(size_t)(r0 + u) * 32 + oc] = acc + b3[oc];
}

extern "C" void kernel_launch(void* const* d_in, const int* in_sizes, int n_in,
                              void* d_out, int out_size, void* d_ws, size_t ws_size,
                              hipStream_t stream) {
  const float* x     = (const float*)d_in[0];
  const float* eattr = (const float*)d_in[1];
  const float* W_h   = (const float*)d_in[2];
  const float* b_h   = (const float*)d_in[3];
  const float* Ws_h  = (const float*)d_in[4];
  const float* bs_h  = (const float*)d_in[5];
  const float* Wb    = (const float*)d_in[6];
  const float* bb    = (const float*)d_in[7];
  const float* Wbs   = (const float*)d_in[8];
  const float* bbs   = (const float*)d_in[9];
  const float* W_f   = (const float*)d_in[10];
  const float* b_f   = (const float*)d_in[11];
  const float* W_fs  = (const float*)d_in[12];
  const float* b_fs  = (const float*)d_in[13];
  const float* W1    = (const float*)d_in[14];
  const float* b1    = (const float*)d_in[15];
  const float* W2    = (const float*)d_in[16];
  const float* b2    = (const float*)d_in[17];
  const float* W3    = (const float*)d_in[18];
  const float* b3    = (const float*)d_in[19];
  const int*   edge  = (const int*)d_in[20];
  const int*   bbox  = (const int*)d_in[21];
  float* out = (float*)d_out;

  // ---- workspace layout (~150 MB; budget >= 233 MB) ----
  _Float16* feats  = (_Float16*)d_ws;                 // [NN_PAD][FUS] f16
  _Float16* sfeats = feats + (size_t)NN_PAD * FUS;    // [NN_PAD][FUS] f16
  float* PQ = (float*)(sfeats + (size_t)NN_PAD * FUS); // 12.8M floats
  _Float16* PQi = (_Float16*)PQ;
  _Float16* Qi  = PQi + (size_t)NN * 256;
  // overlays inside PQ (live only AFTER the last k_conv2):
  float* sb   = PQ;
  float* fsup = sb + (size_t)NB * FUS;
  float* h1   = fsup + (size_t)NB * 1024;
  float* h2b  = h1 + (size_t)NB * 512;
  _Float16* bbH = (_Float16*)(h2b + (size_t)NB * 256);
  _Float16* W1H = bbH + (size_t)NB_PAD * K1;          // ends ~31.9MB
  _Float16* WfH = (_Float16*)PQ + (size_t)784 * 12 * 2048;  // at 38.5MB
  float* pooled = (float*)(WfH + (size_t)FUS * 1024);
  // CSR payload + misc after PQ region:
  _Float16* sea8 = (_Float16*)(PQ + (size_t)2 * NN * CH);
  int* ssrc    = (int*)(sea8 + (size_t)NE * 8);
  int* row_ptr = ssrc + NE;
  int* deg     = row_ptr + NN + 1;
  int* cursor  = deg + NN;
  int* seg     = cursor + NN;
  _Float16* WcatN = (_Float16*)(seg + NB + 1);        // 2 blocks x 128x256
  _Float16* WcatS = WcatN + (size_t)2 * 128 * 256;
  int* bsum = (int*)(WcatS + (size_t)2 * 128 * 256);
  _Float16* sbH = (_Float16*)(((uintptr_t)(bsum + SCAN_NBLK) + 127) &
                              ~(uintptr_t)127);       // [NB_PAD][FUS] f16
  _Float16* WfsH = sbH + (size_t)NB_PAD * FUS;        // 384x1024 B-frags

  hipMemsetAsync(deg, 0, 2 * NN * sizeof(int), stream);  // deg + cursor
  // zero the feats16 pad rows (read by pool_mfma)
  hipMemsetAsync(feats + (size_t)NN * FUS, 0,
                 (size_t)(NN_PAD - NN) * FUS * sizeof(_Float16), stream);

  // ---- CSR build (dst-sorted payload, parallel scan) + bbox segments ----
  k_deg<<<(NE + 255) / 256, 256, 0, stream>>>(edge, deg);
  k_scan1<<<SCAN_NBLK, 1024, 0, stream>>>(deg, row_ptr, bsum);
  k_scan2<<<1, 64, 0, stream>>>(bsum);
  k_scan3<<<(NN + 255) / 256, 256, 0, stream>>>(bsum, row_ptr);
  k_fill<<<(NE + 255) / 256, 256, 0, stream>>>(edge, eattr, row_ptr, cursor,
                                               ssrc, sea8);
  k_segstart<<<(NN + 255) / 256, 256, 0, stream>>>(bbox, seg);

  const int npq_grid = (NN + 31) / 32;

  // ---- conv 0 (head): both streams in one launch (blockIdx.y = sel) ----
  k_node_pq<<<dim3(npq_grid, 2), 256, 0, stream>>>(x, INCH, INCH, W_h, b_h,
                                                   Ws_h, bs_h, PQi, Qi);
  k_conv2<<<NN / 4, 256, 0, stream>>>(row_ptr, ssrc, sea8, PQi, Qi,
                                      W_h + 2 * INCH * CH, Ws_h + 2 * INCH * CH,
                                      feats, sfeats, 0, -1);

  // ---- residual blocks (K=128): weight prep hoisted, both blocks ----
  k_cvtWnpq<<<dim3(64, 2, 2), 64, 0, stream>>>(Wb, Wbs, WcatN, WcatS);
  for (int i = 0; i < 2; ++i) {
    const float* Wi  = Wb  + (size_t)i * 262 * CH;
    const float* bi  = bb  + (size_t)i * CH;
    const float* Wsi = Wbs + (size_t)i * 262 * CH;
    const float* bsi = bbs + (size_t)i * CH;
    k_npq_mfma<<<dim3((NN + 63) / 64, 2), 256, 0, stream>>>(
        feats + i * CH, sfeats + i * CH, FUS, WcatN + (size_t)i * 32768,
        WcatS + (size_t)i * 32768, bi, bsi, PQi, Qi);
    k_conv2<<<NN / 4, 256, 0, stream>>>(row_ptr, ssrc, sea8, PQi, Qi,
                                        Wi + 2 * CH * CH, Wsi + 2 * CH * CH,
                                        feats, sfeats, i + 1, i);
  }

  // ---- pooling: barrier-free MFMA GEMM from feats16 + phase-carry atomics ----
  k_cvtB2<1024, 64><<<dim3(12 * 64, 2), 64, 0, stream>>>(W_f, W_fs, WfH, WfsH);
  hipMemsetAsync(pooled, 0, (size_t)NB * 1408 * sizeof(float), stream);
  k_pool_mfma<<<784 * 8, 256, 0, stream>>>(feats, WfH, bbox, b_f, pooled);
  k_poolraw<<<NB, 256, 0, stream>>>(feats, sfeats, seg, pooled, sb, sbH);
  k_fsup_mfma<<<dim3(NB_PAD / 64, 8), 256, 0, stream>>>(sbH, WfsH, b_fs, fsup);

  // ---- head MLP: concat->f16, W1->f16 frag, MFMA GEMM, then small MLPs ----
  k_cvt_cat<<<(int)(((size_t)NB_PAD * K1 / 8) / 256), 256, 0, stream>>>(
      pooled, fsup, sb, bbH);
  k_cvtB<512, 32><<<88 * 32, 64, 0, stream>>>(W1, W1H);
  k_mlp1_mfma<<<dim3(NB_PAD / 64, 4), 256, 0, stream>>>(bbH, W1H, b1, h1);
  k_mlp2<<<NB / 8, 256, 0, stream>>>(h1, W2, b2, h2b);
  k_mlp3<<<NB / 8, 256, 0, stream>>>(h2b, W3, b3, out);
}

// Round 11
// 772.261 us; speedup vs baseline: 1.0594x; 1.0594x over previous
//
#include <hip/hip_runtime.h>
#include <stdint.h>

#define NN      50000
#define NN_PAD  50176   // 784 * 64
#define NE      800000
#define INCH    8
#define CH      128
#define EA      6
#define NB      2000
#define NB_PAD  2048
#define NCLS    32
#define FUS     384
#define K1      2816   // 1408 + 1024 + 384
#define SCAN_NBLK 49   // (NN + 1023) / 1024

typedef _Float16 half8 __attribute__((ext_vector_type(8)));
typedef _Float16 h2 __attribute__((ext_vector_type(2)));
typedef float f32x4 __attribute__((ext_vector_type(4)));

// ---------- degree of dst nodes ----------
__global__ __launch_bounds__(256) void k_deg(const int* __restrict__ edge,
                                             int* __restrict__ deg) {
  int e = blockIdx.x * 256 + threadIdx.x;
  if (e < NE) atomicAdd(&deg[edge[NE + e]], 1);
}

// ---------- parallel scan, phase 1: per-block inclusive scan + block sums ----
__global__ __launch_bounds__(1024) void k_scan1(const int* __restrict__ deg,
                                                int* __restrict__ row_ptr,
                                                int* __restrict__ bsum) {
  __shared__ int wsum[16];
  const int t = threadIdx.x, lane = t & 63, w = t >> 6;
  const int i = blockIdx.x * 1024 + t;
  int x = (i < NN) ? deg[i] : 0;
#pragma unroll
  for (int off = 1; off < 64; off <<= 1) {
    int y = __shfl_up(x, off, 64);
    if (lane >= off) x += y;
  }
  if (lane == 63) wsum[w] = x;
  __syncthreads();
  if (w == 0 && lane < 16) {
    int s = wsum[lane];
#pragma unroll
    for (int off = 1; off < 16; off <<= 1) {
      int y = __shfl_up(s, off, 64);
      if (lane >= off) s += y;
    }
    wsum[lane] = s;
  }
  __syncthreads();
  int incl = x + ((w == 0) ? 0 : wsum[w - 1]);
  if (i < NN) row_ptr[i + 1] = incl;
  if (t == 1023) bsum[blockIdx.x] = incl;
}

// ---------- phase 2: single-wave exclusive scan of block sums ----------
__global__ __launch_bounds__(64) void k_scan2(int* __restrict__ bsum) {
  const int t = threadIdx.x;
  int x = (t < SCAN_NBLK) ? bsum[t] : 0;
#pragma unroll
  for (int off = 1; off < 64; off <<= 1) {
    int y = __shfl_up(x, off, 64);
    if (t >= off) x += y;
  }
  int ex = __shfl_up(x, 1, 64);
  if (t == 0) ex = 0;
  if (t < SCAN_NBLK) bsum[t] = ex;
}

// ---------- phase 3: add block offsets ----------
__global__ __launch_bounds__(256) void k_scan3(const int* __restrict__ bsum,
                                               int* __restrict__ row_ptr) {
  const int i = blockIdx.x * 256 + threadIdx.x;
  if (i == 0) row_ptr[0] = 0;
  if (i < NN) row_ptr[i + 1] += bsum[i >> 10];
}

// ---------- fill CSR payload: dst-sorted src + f16 e_attr ----------
__global__ __launch_bounds__(256) void k_fill(
    const int* __restrict__ edge, const float* __restrict__ eattr,
    const int* __restrict__ row_ptr, int* __restrict__ cursor,
    int* __restrict__ ssrc, _Float16* __restrict__ sea8) {
  int e = blockIdx.x * 256 + threadIdx.x;
  if (e >= NE) return;
  int s = edge[e], d = edge[NE + e];
  int idx = row_ptr[d] + atomicAdd(&cursor[d], 1);
  ssrc[idx] = s;
  half8 v;
#pragma unroll
  for (int j = 0; j < EA; ++j) v[j] = (_Float16)eattr[(size_t)e * EA + j];
  v[6] = (_Float16)0.f; v[7] = (_Float16)0.f;
  *(half8*)(sea8 + (size_t)idx * 8) = v;
}

// ---------- segment starts from sorted bbox_idx ----------
__global__ __launch_bounds__(256) void k_segstart(const int* __restrict__ bbox,
                                                  int* __restrict__ seg) {
  int i = blockIdx.x * 256 + threadIdx.x;
  if (i >= NN) return;
  int bc = bbox[i];
  int bp = (i == 0) ? -1 : bbox[i - 1];
  for (int j = bp + 1; j <= bc; ++j) seg[j] = i;
  if (i == NN - 1)
    for (int j = bc + 1; j <= NB; ++j) seg[j] = NN;
}

// ---------- head node transform (K=8), both streams via blockIdx.y ----------
__global__ __launch_bounds__(256) void k_node_pq(
    const float* __restrict__ X, int ldx, int K,
    const float* __restrict__ WN, const float* __restrict__ bN,
    const float* __restrict__ WS, const float* __restrict__ bS,
    _Float16* __restrict__ PQi, _Float16* __restrict__ Qi) {
  const int sel = blockIdx.y;
  const float* W = sel ? WS : WN;
  const float* bias = sel ? bS : bN;
  const int t = threadIdx.x, lane = t & 63, wv = t >> 6;
  const int nbase = blockIdx.x * 32 + wv * 8;
  const int c = lane * 2;
  const float2 bv = *(const float2*)(bias + c);
  float2 pacc[8], qacc[8];
#pragma unroll
  for (int u = 0; u < 8; ++u) { pacc[u] = bv; qacc[u] = make_float2(0.f, 0.f); }
  const int xrow = min(nbase + (lane >> 3), NN - 1);
  const int xk = lane & 7;
  for (int k0 = 0; k0 < K; k0 += 8) {
    const float xv = X[(size_t)xrow * ldx + k0 + xk];
#pragma unroll
    for (int j = 0; j < 8; ++j) {
      const float2 w1 = *(const float2*)(W + (size_t)(k0 + j) * CH + c);
      const float2 w2 = *(const float2*)(W + (size_t)(K + k0 + j) * CH + c);
      const float2 wd = {w1.x - w2.x, w1.y - w2.y};
#pragma unroll
      for (int u = 0; u < 8; ++u) {
        const float xs = __shfl(xv, u * 8 + j, 64);
        pacc[u].x += xs * wd.x; pacc[u].y += xs * wd.y;
        qacc[u].x += xs * w2.x; qacc[u].y += xs * w2.y;
      }
    }
  }
#pragma unroll
  for (int u = 0; u < 8; ++u) {
    const int node = nbase + u;
    if (node < NN) {
      const size_t o = ((size_t)node * 64 + lane) * 4 + sel * 2;
      *(h2*)(PQi + o) = (h2){(_Float16)pacc[u].x, (_Float16)pacc[u].y};
      *(h2*)(Qi + o)  = (h2){(_Float16)qacc[u].x, (_Float16)qacc[u].y};
    }
  }
}

// ---------- pack [W1-W2 | W2] into f16 B-frags, both res-blocks (z) ----------
__global__ __launch_bounds__(64) void k_cvtWnpq(
    const float* __restrict__ WbAll, const float* __restrict__ WbsAll,
    _Float16* __restrict__ whN, _Float16* __restrict__ whS) {
  const int blk = blockIdx.z;
  const float* W = (blockIdx.y ? WbsAll : WbAll) + (size_t)blk * 262 * CH;
  _Float16* wh   = (blockIdx.y ? whS : whN) + (size_t)blk * 32768;
  const int c = blockIdx.x >> 4, tile = blockIdx.x & 15;
  const int L = threadIdx.x;
  const int n = tile * 16 + (L & 15);
  const int k0 = c * 32 + (L >> 4) * 8;
  half8 v;
#pragma unroll
  for (int j = 0; j < 8; ++j) {
    const int k = k0 + j;
    float val;
    if (n < CH) val = W[(size_t)k * CH + n] - W[(size_t)(CH + k) * CH + n];
    else        val = W[(size_t)(CH + k) * CH + (n - CH)];
    v[j] = (_Float16)val;
  }
  *(half8*)(wh + (((size_t)(c * 16 + tile)) * 64 + L) * 8) = v;
}

// ---------- residual node transform on matrix cores (both streams) ----------
// R7: X is f16 row-major [node][FUS] -> direct half8 A loads, no cvts.
__global__ __launch_bounds__(256) void k_npq_mfma(
    const _Float16* __restrict__ Xn, const _Float16* __restrict__ Xs, int ldx,
    const _Float16* __restrict__ whN, const _Float16* __restrict__ whS,
    const float* __restrict__ biasN, const float* __restrict__ biasS,
    _Float16* __restrict__ PQi, _Float16* __restrict__ Qi) {
  const int sel = blockIdx.y;
  const _Float16* X = sel ? Xs : Xn;
  const _Float16* wh = sel ? whS : whN;
  const float* bias = sel ? biasS : biasN;
  const int t = threadIdx.x, lane = t & 63, wv = t >> 6;
  const int nbase = blockIdx.x * 64;
  const int m = lane & 15, quad = lane >> 4;
  f32x4 acc[4][4];
#pragma unroll
  for (int i = 0; i < 4; ++i)
#pragma unroll
    for (int nt = 0; nt < 4; ++nt) acc[i][nt] = (f32x4){0.f, 0.f, 0.f, 0.f};
#pragma unroll
  for (int ks = 0; ks < 4; ++ks) {
    half8 b[4];
#pragma unroll
    for (int nt = 0; nt < 4; ++nt)
      b[nt] = *(const half8*)(wh + (((size_t)(ks * 16 + wv * 4 + nt)) * 64 + lane) * 8);
#pragma unroll
    for (int i = 0; i < 4; ++i) {
      const int row = min(nbase + i * 16 + m, NN - 1);
      const half8 a = *(const half8*)(X + (size_t)row * ldx + ks * 32 + quad * 8);
#pragma unroll
      for (int nt = 0; nt < 4; ++nt)
        acc[i][nt] = __builtin_amdgcn_mfma_f32_16x16x32_f16(a, b[nt], acc[i][nt],
                                                            0, 0, 0);
    }
  }
#pragma unroll
  for (int i = 0; i < 4; ++i)
#pragma unroll
    for (int nt = 0; nt < 4; ++nt) {
      const int col = wv * 64 + nt * 16 + m;
      const float bv = (col < CH) ? bias[col] : 0.f;
#pragma unroll
      for (int r = 0; r < 4; ++r) {
        const int row = nbase + i * 16 + quad * 4 + r;
        if (row < NN) {
          const float v = acc[i][nt][r] + bv;
          if (col < CH)
            PQi[((size_t)row * 64 + (col >> 1)) * 4 + sel * 2 + (col & 1)] =
                (_Float16)v;
          else {
            const int qc = col - CH;
            Qi[((size_t)row * 64 + (qc >> 1)) * 4 + sel * 2 + (qc & 1)] =
                (_Float16)v;
          }
        }
      }
    }
}

// ---------- fused dual-stream CSR conv ----------
// R2: packed-f16 edge math + gather prefetch. R7: f16 feats + 8-deep gathers.
__global__ __launch_bounds__(256) void k_conv2(
    const int* __restrict__ row_ptr, const int* __restrict__ ssrc,
    const _Float16* __restrict__ sea8,
    const _Float16* __restrict__ PQi, const _Float16* __restrict__ Qi,
    const float* __restrict__ Cn, const float* __restrict__ Cs,
    _Float16* __restrict__ feats, _Float16* __restrict__ sfeats,
    int cur, int prev) {
  const int t = threadIdx.x;
  const int lane = t & 63;
  const int node = blockIdx.x * 4 + (t >> 6);
  const int c = lane * 2;
  h2 cwnh[EA], cwsh[EA];
#pragma unroll
  for (int j = 0; j < EA; ++j) {
    const float2 a = *(const float2*)(Cn + j * CH + c);
    const float2 b = *(const float2*)(Cs + j * CH + c);
    cwnh[j] = (h2){(_Float16)a.x, (_Float16)a.y};
    cwsh[j] = (h2){(_Float16)b.x, (_Float16)b.y};
  }
  int i0 = __builtin_amdgcn_readfirstlane(row_ptr[node]);
  int i1 = __builtin_amdgcn_readfirstlane(row_ptr[node + 1]);
  const uint2 qv = *(const uint2*)(Qi + ((size_t)node * 64 + lane) * 4);
  const h2 qnh = *(const h2*)&qv.x;
  const h2 qsh = *(const h2*)&qv.y;
  const _Float16* pqL = PQi + (size_t)lane * 4;  // + s*256 per edge
  h2 anh = (h2){(_Float16)0.f, (_Float16)0.f};
  float as0 = 0.f, as1 = 0.f;
  const h2 zero = (h2){(_Float16)0.f, (_Float16)0.f};
#define COMP(PV, J)                                                        \
  {                                                                        \
    unsigned w0 = __shfl((int)ea_l.x, (J), 64);                            \
    unsigned w1 = __shfl((int)ea_l.y, (J), 64);                            \
    unsigned w2 = __shfl((int)ea_l.z, (J), 64);                            \
    const h2 ea01 = *(const h2*)&w0;                                       \
    const h2 ea23 = *(const h2*)&w1;                                       \
    const h2 ea45 = *(const h2*)&w2;                                       \
    h2 vn = *(const h2*)&PV.x + qnh;                                       \
    h2 vs = *(const h2*)&PV.y + qsh;                                       \
    h2 b;                                                                  \
    b = (h2){ea01[0], ea01[0]}; vn += b * cwnh[0]; vs += b * cwsh[0];      \
    b = (h2){ea01[1], ea01[1]}; vn += b * cwnh[1]; vs += b * cwsh[1];      \
    b = (h2){ea23[0], ea23[0]}; vn += b * cwnh[2]; vs += b * cwsh[2];      \
    b = (h2){ea23[1], ea23[1]}; vn += b * cwnh[3]; vs += b * cwsh[3];      \
    b = (h2){ea45[0], ea45[0]}; vn += b * cwnh[4]; vs += b * cwsh[4];      \
    b = (h2){ea45[1], ea45[1]}; vn += b * cwnh[5]; vs += b * cwsh[5];      \
    anh = __builtin_elementwise_max(anh, vn);                              \
    const h2 vsr = __builtin_elementwise_max(vs, zero);                    \
    as0 += (float)vsr[0]; as1 += (float)vsr[1];                            \
  }
  for (int base = i0; base < i1; base += 64) {
    const int cnt = min(64, i1 - base);
    int s_l = 0;
    uint4 ea_l = {0u, 0u, 0u, 0u};
    if (lane < cnt) {
      s_l = ssrc[base + lane];
      ea_l = *(const uint4*)(sea8 + (size_t)(base + lane) * 8);
    }
    int j = 0;
    for (; j + 8 <= cnt; j += 8) {
      // 8 independent row gathers in flight before any compute
      const int s0 = __shfl(s_l, j, 64),     s1 = __shfl(s_l, j + 1, 64);
      const int s2 = __shfl(s_l, j + 2, 64), s3 = __shfl(s_l, j + 3, 64);
      const int s4 = __shfl(s_l, j + 4, 64), s5 = __shfl(s_l, j + 5, 64);
      const int s6 = __shfl(s_l, j + 6, 64), s7 = __shfl(s_l, j + 7, 64);
      const uint2 p0 = *(const uint2*)(pqL + (size_t)s0 * 256);
      const uint2 p1 = *(const uint2*)(pqL + (size_t)s1 * 256);
      const uint2 p2 = *(const uint2*)(pqL + (size_t)s2 * 256);
      const uint2 p3 = *(const uint2*)(pqL + (size_t)s3 * 256);
      const uint2 p4 = *(const uint2*)(pqL + (size_t)s4 * 256);
      const uint2 p5 = *(const uint2*)(pqL + (size_t)s5 * 256);
      const uint2 p6 = *(const uint2*)(pqL + (size_t)s6 * 256);
      const uint2 p7 = *(const uint2*)(pqL + (size_t)s7 * 256);
      COMP(p0, j)     COMP(p1, j + 1) COMP(p2, j + 2) COMP(p3, j + 3)
      COMP(p4, j + 4) COMP(p5, j + 5) COMP(p6, j + 6) COMP(p7, j + 7)
    }
    for (; j + 4 <= cnt; j += 4) {
      const int s0 = __shfl(s_l, j, 64),     s1 = __shfl(s_l, j + 1, 64);
      const int s2 = __shfl(s_l, j + 2, 64), s3 = __shfl(s_l, j + 3, 64);
      const uint2 p0 = *(const uint2*)(pqL + (size_t)s0 * 256);
      const uint2 p1 = *(const uint2*)(pqL + (size_t)s1 * 256);
      const uint2 p2 = *(const uint2*)(pqL + (size_t)s2 * 256);
      const uint2 p3 = *(const uint2*)(pqL + (size_t)s3 * 256);
      COMP(p0, j) COMP(p1, j + 1) COMP(p2, j + 2) COMP(p3, j + 3)
    }
    for (; j < cnt; ++j) {
      const int s0 = __shfl(s_l, j, 64);
      const uint2 p0 = *(const uint2*)(pqL + (size_t)s0 * 256);
      COMP(p0, j)
    }
  }
#undef COMP
  float an0 = (float)anh[0], an1 = (float)anh[1];
  const float inv = 1.f / fmaxf((float)(i1 - i0), 1.f);
  as0 *= inv; as1 *= inv;
  const size_t o = (size_t)node * FUS + (size_t)cur * CH + c;
  if (prev >= 0) {
    const size_t op = (size_t)node * FUS + (size_t)prev * CH + c;
    const h2 prn = *(const h2*)(feats + op);
    const h2 prs = *(const h2*)(sfeats + op);
    an0 += (float)prn[0]; an1 += (float)prn[1];
    as0 += (float)prs[0]; as1 += (float)prs[1];
  }
  *(h2*)(feats + o)  = (h2){(_Float16)an0, (_Float16)an1};
  *(h2*)(sfeats + o) = (h2){(_Float16)as0, (_Float16)as1};
}

// ---------- convert + pack W (KxN f32) into f16 B-fragment order ----------
template <int N, int NT>
__global__ __launch_bounds__(64) void k_cvtB(const float* __restrict__ W,
                                             _Float16* __restrict__ wh) {
  const int c = blockIdx.x / NT;
  const int tile = blockIdx.x % NT;
  const int L = threadIdx.x;
  const int n = tile * 16 + (L & 15);
  const int k0 = c * 32 + (L >> 4) * 8;
  half8 v;
#pragma unroll
  for (int j = 0; j < 8; ++j) v[j] = (_Float16)W[(size_t)(k0 + j) * N + n];
  *(half8*)(wh + (((size_t)(c * NT + tile)) * 64 + L) * 8) = v;
}

// ---------- dual-source variant (merged launch for W_f / W_fs) ----------
template <int N, int NT>
__global__ __launch_bounds__(64) void k_cvtB2(const float* __restrict__ WA,
                                              const float* __restrict__ WB,
                                              _Float16* __restrict__ whA,
                                              _Float16* __restrict__ whB) {
  const float* W = blockIdx.y ? WB : WA;
  _Float16* wh   = blockIdx.y ? whB : whA;
  const int c = blockIdx.x / NT;
  const int tile = blockIdx.x % NT;
  const int L = threadIdx.x;
  const int n = tile * 16 + (L & 15);
  const int k0 = c * 32 + (L >> 4) * 8;
  half8 v;
#pragma unroll
  for (int j = 0; j < 8; ++j) v[j] = (_Float16)W[(size_t)(k0 + j) * N + n];
  *(half8*)(wh + (((size_t)(c * NT + tile)) * 64 + L) * 8) = v;
}

// ---------- fusion GEMM + segment max ----
// R10: REVERT to the R8 structure (measured 75.4us) after R9's barrier-free
// 2x2 partition regressed to 119us -- barriers were NOT the bottleneck
// (staggered blocks cover each other's drains); doubling per-wave VMEM
// issue was. R8 = LDS-staged A (wave wv stages frag i==wv), double-buffered,
// 2-deep prefetch, phase-carry run-merged atomicMax epilogue. Pool is a
// composite floor (~26us L2 + ~15-20us L3 A-stream + ~19us MFMA, partially
// overlapped); occupancy/ILP/atomics/barriers all individually falsified.
__global__ __launch_bounds__(256, 6) void k_pool_mfma(
    const _Float16* __restrict__ feats16, const _Float16* __restrict__ wh,
    const int* __restrict__ bbox, const float* __restrict__ bf,
    float* __restrict__ pooled) {
  __shared__ float cl[32 * 132];
  __shared__ int s_bb[64];
  _Float16* abuf = (_Float16*)cl;  // 2 x 2048 halves (8KB), K-loop life only
  const int t = threadIdx.x, lane = t & 63, wv = t >> 6;
  const int fid = blockIdx.x;
  const int xcd = fid & 7, slot = fid >> 3;
  const int cg = slot & 7;
  const int rb = xcd * 98 + (slot >> 3);
  const int nbase = rb * 64;
  const int m = lane & 15, quad = lane >> 4;
  if (t < 64) s_bb[t] = bbox[min(nbase + t, NN - 1)];
  f32x4 acc[4][2];
#pragma unroll
  for (int i = 0; i < 4; ++i)
#pragma unroll
    for (int nt = 0; nt < 2; ++nt) acc[i][nt] = (f32x4){0.f, 0.f, 0.f, 0.f};
  // wave wv stages fragment i==wv of each K-chunk, from row-major feats16
  const _Float16* apc = feats16 + (size_t)(nbase + wv * 16 + m) * FUS + quad * 8;
  const _Float16* bp = wh + ((size_t)(cg * 8 + wv * 2) * 64 + lane) * 8;
  _Float16* wslot = abuf + wv * 512 + lane * 8;
  const _Float16* rbase = abuf + lane * 8;
  half8 b0 = *(const half8*)(bp);
  half8 b1 = *(const half8*)(bp + 512);
  half8 rA = *(const half8*)(apc);             // chunk 0 quarter
  *(half8*)(wslot) = rA;                       // -> buf0
  half8 rN = *(const half8*)(apc + 32);        // chunk 1 quarter
  __syncthreads();                             // buf0 ready (+ s_bb ordered)
#pragma unroll
  for (int ks = 0; ks < 12; ++ks) {
    const int cur = ks & 1;
    half8 nb0, nb1;
    if (ks < 11) {
      nb0 = *(const half8*)(bp + (size_t)(ks + 1) * 32768);
      nb1 = *(const half8*)(bp + (size_t)(ks + 1) * 32768 + 512);
    }
#pragma unroll
    for (int i = 0; i < 4; ++i) {
      const half8 a = *(const half8*)(rbase + cur * 2048 + i * 512);
      acc[i][0] = __builtin_amdgcn_mfma_f32_16x16x32_f16(a, b0, acc[i][0], 0, 0, 0);
      acc[i][1] = __builtin_amdgcn_mfma_f32_16x16x32_f16(a, b1, acc[i][1], 0, 0, 0);
    }
    if (ks < 11) {
      *(half8*)(wslot + (cur ^ 1) * 2048) = rN;   // stage chunk ks+1
      b0 = nb0; b1 = nb1;
    }
    if (ks < 10) rN = *(const half8*)(apc + (size_t)(ks + 2) * 32);
    __syncthreads();   // buf[cur^1] ready; all reads of buf[cur] done
  }
  const int col = t & 127, rh = t >> 7;
  const int gcol = cg * 128 + col;
  const float bias = bf[gcol];
  int curb = -1;
  float mx = 0.f;
#pragma unroll
  for (int p = 0; p < 2; ++p) {
    __syncthreads();  // p=1: phase-0 readers done with cl
#pragma unroll
    for (int ii = 0; ii < 2; ++ii)
#pragma unroll
      for (int nt = 0; nt < 2; ++nt) {
        const int scol = wv * 32 + nt * 16 + m;
#pragma unroll
        for (int r = 0; r < 4; ++r)
          cl[(ii * 16 + quad * 4 + r) * 132 + scol] = acc[p + 2 * ii][nt][r];
      }
    __syncthreads();
    for (int rr = 0; rr < 16; ++rr) {
      const int g = rh * 32 + p * 16 + rr;   // contiguous per-thread span
      const int node = nbase + g;
      if (node >= NN) break;
      const int bid = s_bb[g];
      const float v = fmaxf(cl[(rh * 16 + rr) * 132 + col] + bias, 0.f);
      if (bid != curb) {
        if (curb >= 0)
          atomicMax((unsigned*)(pooled + (size_t)curb * 1408 + gcol),
                    __float_as_uint(mx));
        curb = bid;
        mx = v;
      } else {
        mx = fmaxf(mx, v);
      }
    }
  }
  if (curb >= 0)
    atomicMax((unsigned*)(pooled + (size_t)curb * 1408 + gcol),
              __float_as_uint(mx));
}

// ---------- raw-feats bbox max + sfeats bbox mean (+ f16 sb copy) ----------
__global__ __launch_bounds__(256) void k_poolraw(
    const _Float16* __restrict__ feats, const _Float16* __restrict__ sfeats,
    const int* __restrict__ seg, float* __restrict__ pooled,
    float* __restrict__ sb, _Float16* __restrict__ sbH) {
  const int b = blockIdx.x, t = threadIdx.x;
  if (t >= 192) return;
  const int c2 = t * 2;
  const int n0 = __builtin_amdgcn_readfirstlane(seg[b]);
  const int n1 = __builtin_amdgcn_readfirstlane(seg[b + 1]);
  float2 fmx = {0.f, 0.f}, ss = {0.f, 0.f};
  for (int n = n0; n < n1; ++n) {
    const h2 f2 = *(const h2*)(feats + (size_t)n * FUS + c2);
    fmx.x = fmaxf(fmx.x, (float)f2[0]); fmx.y = fmaxf(fmx.y, (float)f2[1]);
    const h2 s2 = *(const h2*)(sfeats + (size_t)n * FUS + c2);
    ss.x += (float)s2[0]; ss.y += (float)s2[1];
  }
  *(float2*)(pooled + (size_t)b * 1408 + 1024 + c2) = fmx;
  const float inv = 1.f / fmaxf((float)(n1 - n0), 1.f);
  float2 o = {ss.x * inv, ss.y * inv};
  *(float2*)(sb + (size_t)b * FUS + c2) = o;
  *(h2*)(sbH + (size_t)b * FUS + c2) = (h2){(_Float16)o.x, (_Float16)o.y};
}

// ---------- fusion_super = relu(sbH @ WfsH + bfs) on matrix cores ----------
__global__ __launch_bounds__(256) void k_fsup_mfma(
    const _Float16* __restrict__ sbH, const _Float16* __restrict__ wh,
    const float* __restrict__ bfs, float* __restrict__ fs) {
  const int t = threadIdx.x, lane = t & 63, wv = t >> 6;
  const int nbase = blockIdx.x * 64;
  const int cg = blockIdx.y;
  const int m = lane & 15, quad = lane >> 4;
  f32x4 acc[4][2];
#pragma unroll
  for (int i = 0; i < 4; ++i)
#pragma unroll
    for (int nt = 0; nt < 2; ++nt) acc[i][nt] = (f32x4){0.f, 0.f, 0.f, 0.f};
  const _Float16* ap = sbH + (size_t)(nbase + m) * FUS + quad * 8;
  const _Float16* bp = wh + ((size_t)(cg * 8 + wv * 2) * 64 + lane) * 8;
#pragma unroll
  for (int ks = 0; ks < 12; ++ks) {
    const half8 b0 = *(const half8*)(bp + (size_t)ks * 32768);
    const half8 b1v = *(const half8*)(bp + (size_t)ks * 32768 + 512);
#pragma unroll
    for (int i = 0; i < 4; ++i) {
      const half8 a = *(const half8*)(ap + (size_t)(i * 16) * FUS + ks * 32);
      acc[i][0] = __builtin_amdgcn_mfma_f32_16x16x32_f16(a, b0, acc[i][0], 0, 0, 0);
      acc[i][1] = __builtin_amdgcn_mfma_f32_16x16x32_f16(a, b1v, acc[i][1], 0, 0, 0);
    }
  }
#pragma unroll
  for (int i = 0; i < 4; ++i)
#pragma unroll
    for (int nt = 0; nt < 2; ++nt) {
      const int gcol = cg * 128 + wv * 32 + nt * 16 + m;
      const float bias = bfs[gcol];
#pragma unroll
      for (int r = 0; r < 4; ++r) {
        const int row = nbase + i * 16 + quad * 4 + r;
        if (row < NB)
          fs[(size_t)row * 1024 + gcol] = fmaxf(acc[i][nt][r] + bias, 0.f);
      }
    }
}

// ---------- concat [pooled | fsup | sb] -> f16 bbH[NB_PAD][K1], zero-padded ----
__global__ __launch_bounds__(256) void k_cvt_cat(
    const float* __restrict__ pooled, const float* __restrict__ fsup,
    const float* __restrict__ sb, _Float16* __restrict__ bbH) {
  const size_t off = ((size_t)blockIdx.x * 256 + threadIdx.x) * 8;
  const int row = (int)(off / K1);
  const int col = (int)(off - (size_t)row * K1);
  half8 v;
  if (row < NB) {
    const float* src;
    if (col < 1408)      src = pooled + (size_t)row * 1408 + col;
    else if (col < 2432) src = fsup + (size_t)row * 1024 + (col - 1408);
    else                 src = sb + (size_t)row * FUS + (col - 2432);
    const float4 f0 = *(const float4*)src;
    const float4 f1 = *(const float4*)(src + 4);
    v[0] = (_Float16)f0.x; v[1] = (_Float16)f0.y;
    v[2] = (_Float16)f0.z; v[3] = (_Float16)f0.w;
    v[4] = (_Float16)f1.x; v[5] = (_Float16)f1.y;
    v[6] = (_Float16)f1.z; v[7] = (_Float16)f1.w;
  } else {
#pragma unroll
    for (int j = 0; j < 8; ++j) v[j] = (_Float16)0.f;
  }
  *(half8*)(bbH + off) = v;
}

// ---------- h1 = relu(bbH @ W1 + b1) on matrix cores ----------
// R10: cols split 4x128 -> 8x64 (grid 32x8 = 256 blocks). The old 128-block
// launch left half the 256 CUs idle; same FLOPs at 2x parallelism.
__global__ __launch_bounds__(256) void k_mlp1_mfma(
    const _Float16* __restrict__ bbH, const _Float16* __restrict__ wh,
    const float* __restrict__ b1, float* __restrict__ h1) {
  const int t = threadIdx.x, lane = t & 63, wv = t >> 6;
  const int nbase = blockIdx.x * 64;
  const int cg = blockIdx.y;           // 8 groups of 64 cols
  const int m = lane & 15, quad = lane >> 4;
  f32x4 acc[4];
#pragma unroll
  for (int i = 0; i < 4; ++i) acc[i] = (f32x4){0.f, 0.f, 0.f, 0.f};
  const _Float16* ap = bbH + (size_t)(nbase + m) * K1 + quad * 8;
  const _Float16* bp = wh + ((size_t)(cg * 4 + wv) * 64 + lane) * 8;
#pragma unroll 4
  for (int ks = 0; ks < 88; ++ks) {
    const half8 b0 = *(const half8*)(bp + (size_t)ks * 16384);
#pragma unroll
    for (int i = 0; i < 4; ++i) {
      const half8 a = *(const half8*)(ap + (size_t)(i * 16) * K1 + ks * 32);
      acc[i] = __builtin_amdgcn_mfma_f32_16x16x32_f16(a, b0, acc[i], 0, 0, 0);
    }
  }
#pragma unroll
  for (int i = 0; i < 4; ++i) {
    const int gcol = cg * 64 + wv * 16 + m;
    const float bias = b1[gcol];
#pragma unroll
    for (int r = 0; r < 4; ++r) {
      const int row = nbase + i * 16 + quad * 4 + r;
      if (row < NB)
        h1[(size_t)row * 512 + gcol] = fmaxf(acc[i][r] + bias, 0.f);
    }
  }
}

// ---------- h2 = relu(h1 @ W2 + b2) ----------
__global__ __launch_bounds__(256) void k_mlp2(
    const float* __restrict__ h1, const float* __restrict__ W2,
    const float* __restrict__ b2, float* __restrict__ h2o) {
  const int r0 = blockIdx.x * 8, t = threadIdx.x;
  float acc[8];
#pragma unroll
  for (int u = 0; u < 8; ++u) acc[u] = 0.f;
  for (int k = 0; k < 512; ++k) {
    float w = W2[(size_t)k * 256 + t];
#pragma unroll
    for (int u = 0; u < 8; ++u) acc[u] += h1[(size_t)(r0 + u) * 512 + k] * w;
  }
  float bv = b2[t];
#pragma unroll
  for (int u = 0; u < 8; ++u)
    h2o[(size_t)(r0 + u) * 256 + t] = fmaxf(acc[u] + bv, 0.f);
}

// ---------- logits = h2 @ W3 + b3 ----------
__global__ __launch_bounds__(256) void k_mlp3(
    const float* __restrict__ h2i, const float* __restrict__ W3,
    const float* __restrict__ b3, float* __restrict__ out) {
  const int r0 = blockIdx.x * 8, t = threadIdx.x;
  const int u = t >> 5, oc = t & 31;
  const float* x = h2i + (size_t)(r0 + u) * 256;
  float acc = 0.f;
  for (int k = 0; k < 256; ++k) acc += x[k] * W3[(size_t)k * 32 + oc];
  out[(size_t)(r0 + u) * 32 + oc] = acc + b3[oc];
}

extern "C" void kernel_launch(void* const* d_in, const int* in_sizes, int n_in,
                              void* d_out, int out_size, void* d_ws, size_t ws_size,
                              hipStream_t stream) {
  const float* x     = (const float*)d_in[0];
  const float* eattr = (const float*)d_in[1];
  const float* W_h   = (const float*)d_in[2];
  const float* b_h   = (const float*)d_in[3];
  const float* Ws_h  = (const float*)d_in[4];
  const float* bs_h  = (const float*)d_in[5];
  const float* Wb    = (const float*)d_in[6];
  const float* bb    = (const float*)d_in[7];
  const float* Wbs   = (const float*)d_in[8];
  const float* bbs   = (const float*)d_in[9];
  const float* W_f   = (const float*)d_in[10];
  const float* b_f   = (const float*)d_in[11];
  const float* W_fs  = (const float*)d_in[12];
  const float* b_fs  = (const float*)d_in[13];
  const float* W1    = (const float*)d_in[14];
  const float* b1    = (const float*)d_in[15];
  const float* W2    = (const float*)d_in[16];
  const float* b2    = (const float*)d_in[17];
  const float* W3    = (const float*)d_in[18];
  const float* b3    = (const float*)d_in[19];
  const int*   edge  = (const int*)d_in[20];
  const int*   bbox  = (const int*)d_in[21];
  float* out = (float*)d_out;

  // ---- workspace layout (~150 MB; budget >= 233 MB) ----
  _Float16* feats  = (_Float16*)d_ws;                 // [NN_PAD][FUS] f16
  _Float16* sfeats = feats + (size_t)NN_PAD * FUS;    // [NN_PAD][FUS] f16
  float* PQ = (float*)(sfeats + (size_t)NN_PAD * FUS); // 12.8M floats
  _Float16* PQi = (_Float16*)PQ;
  _Float16* Qi  = PQi + (size_t)NN * 256;
  // overlays inside PQ (live only AFTER the last k_conv2):
  float* sb   = PQ;
  float* fsup = sb + (size_t)NB * FUS;
  float* h1   = fsup + (size_t)NB * 1024;
  float* h2b  = h1 + (size_t)NB * 512;
  _Float16* bbH = (_Float16*)(h2b + (size_t)NB * 256);
  _Float16* W1H = bbH + (size_t)NB_PAD * K1;          // ends ~31.9MB
  _Float16* WfH = (_Float16*)PQ + (size_t)784 * 12 * 2048;  // at 38.5MB
  float* pooled = (float*)(WfH + (size_t)FUS * 1024);
  // CSR payload + misc after PQ region:
  _Float16* sea8 = (_Float16*)(PQ + (size_t)2 * NN * CH);
  int* ssrc    = (int*)(sea8 + (size_t)NE * 8);
  int* row_ptr = ssrc + NE;
  int* deg     = row_ptr + NN + 1;
  int* cursor  = deg + NN;
  int* seg     = cursor + NN;
  _Float16* WcatN = (_Float16*)(seg + NB + 1);        // 2 blocks x 128x256
  _Float16* WcatS = WcatN + (size_t)2 * 128 * 256;
  int* bsum = (int*)(WcatS + (size_t)2 * 128 * 256);
  _Float16* sbH = (_Float16*)(((uintptr_t)(bsum + SCAN_NBLK) + 127) &
                              ~(uintptr_t)127);       // [NB_PAD][FUS] f16
  _Float16* WfsH = sbH + (size_t)NB_PAD * FUS;        // 384x1024 B-frags

  hipMemsetAsync(deg, 0, 2 * NN * sizeof(int), stream);  // deg + cursor
  // zero the feats16 pad rows (read by pool_mfma staging)
  hipMemsetAsync(feats + (size_t)NN * FUS, 0,
                 (size_t)(NN_PAD - NN) * FUS * sizeof(_Float16), stream);

  // ---- CSR build (dst-sorted payload, parallel scan) + bbox segments ----
  k_deg<<<(NE + 255) / 256, 256, 0, stream>>>(edge, deg);
  k_scan1<<<SCAN_NBLK, 1024, 0, stream>>>(deg, row_ptr, bsum);
  k_scan2<<<1, 64, 0, stream>>>(bsum);
  k_scan3<<<(NN + 255) / 256, 256, 0, stream>>>(bsum, row_ptr);
  k_fill<<<(NE + 255) / 256, 256, 0, stream>>>(edge, eattr, row_ptr, cursor,
                                               ssrc, sea8);
  k_segstart<<<(NN + 255) / 256, 256, 0, stream>>>(bbox, seg);

  const int npq_grid = (NN + 31) / 32;

  // ---- conv 0 (head): both streams in one launch (blockIdx.y = sel) ----
  k_node_pq<<<dim3(npq_grid, 2), 256, 0, stream>>>(x, INCH, INCH, W_h, b_h,
                                                   Ws_h, bs_h, PQi, Qi);
  k_conv2<<<NN / 4, 256, 0, stream>>>(row_ptr, ssrc, sea8, PQi, Qi,
                                      W_h + 2 * INCH * CH, Ws_h + 2 * INCH * CH,
                                      feats, sfeats, 0, -1);

  // ---- residual blocks (K=128): weight prep hoisted, both blocks ----
  k_cvtWnpq<<<dim3(64, 2, 2), 64, 0, stream>>>(Wb, Wbs, WcatN, WcatS);
  for (int i = 0; i < 2; ++i) {
    const float* Wi  = Wb  + (size_t)i * 262 * CH;
    const float* bi  = bb  + (size_t)i * CH;
    const float* Wsi = Wbs + (size_t)i * 262 * CH;
    const float* bsi = bbs + (size_t)i * CH;
    k_npq_mfma<<<dim3((NN + 63) / 64, 2), 256, 0, stream>>>(
        feats + i * CH, sfeats + i * CH, FUS, WcatN + (size_t)i * 32768,
        WcatS + (size_t)i * 32768, bi, bsi, PQi, Qi);
    k_conv2<<<NN / 4, 256, 0, stream>>>(row_ptr, ssrc, sea8, PQi, Qi,
                                        Wi + 2 * CH * CH, Wsi + 2 * CH * CH,
                                        feats, sfeats, i + 1, i);
  }

  // ---- pooling: MFMA GEMM direct from feats16 + phase-carry atomicMax ----
  k_cvtB2<1024, 64><<<dim3(12 * 64, 2), 64, 0, stream>>>(W_f, W_fs, WfH, WfsH);
  hipMemsetAsync(pooled, 0, (size_t)NB * 1408 * sizeof(float), stream);
  k_pool_mfma<<<784 * 8, 256, 0, stream>>>(feats, WfH, bbox, b_f, pooled);
  k_poolraw<<<NB, 256, 0, stream>>>(feats, sfeats, seg, pooled, sb, sbH);
  k_fsup_mfma<<<dim3(NB_PAD / 64, 8), 256, 0, stream>>>(sbH, WfsH, b_fs, fsup);

  // ---- head MLP: concat->f16, W1->f16 frag, MFMA GEMM, then small MLPs ----
  k_cvt_cat<<<(int)(((size_t)NB_PAD * K1 / 8) / 256), 256, 0, stream>>>(
      pooled, fsup, sb, bbH);
  k_cvtB<512, 32><<<88 * 32, 64, 0, stream>>>(W1, W1H);
  k_mlp1_mfma<<<dim3(NB_PAD / 64, 8), 256, 0, stream>>>(bbH, W1H, b1, h1);
  k_mlp2<<<NB / 8, 256, 0, stream>>>(h1, W2, b2, h2b);
  k_mlp3<<<NB / 8, 256, 0, stream>>>(h2b, W3, b3, out);
}

// Round 12
// 767.175 us; speedup vs baseline: 1.0664x; 1.0066x over previous
//
#include <hip/hip_runtime.h>
#include <stdint.h>

#define NN      50000
#define NN_PAD  50176   // 784 * 64
#define NE      800000
#define INCH    8
#define CH      128
#define EA      6
#define NB      2000
#define NB_PAD  2048
#define NCLS    32
#define FUS     384
#define K1      2816   // 1408 + 1024 + 384
#define SCAN_NBLK 49   // (NN + 1023) / 1024

typedef _Float16 half8 __attribute__((ext_vector_type(8)));
typedef _Float16 h2 __attribute__((ext_vector_type(2)));
typedef float f32x4 __attribute__((ext_vector_type(4)));

// ---------- degree of dst nodes ----------
__global__ __launch_bounds__(256) void k_deg(const int* __restrict__ edge,
                                             int* __restrict__ deg) {
  int e = blockIdx.x * 256 + threadIdx.x;
  if (e < NE) atomicAdd(&deg[edge[NE + e]], 1);
}

// ---------- parallel scan, phase 1: per-block inclusive scan + block sums ----
__global__ __launch_bounds__(1024) void k_scan1(const int* __restrict__ deg,
                                                int* __restrict__ row_ptr,
                                                int* __restrict__ bsum) {
  __shared__ int wsum[16];
  const int t = threadIdx.x, lane = t & 63, w = t >> 6;
  const int i = blockIdx.x * 1024 + t;
  int x = (i < NN) ? deg[i] : 0;
#pragma unroll
  for (int off = 1; off < 64; off <<= 1) {
    int y = __shfl_up(x, off, 64);
    if (lane >= off) x += y;
  }
  if (lane == 63) wsum[w] = x;
  __syncthreads();
  if (w == 0 && lane < 16) {
    int s = wsum[lane];
#pragma unroll
    for (int off = 1; off < 16; off <<= 1) {
      int y = __shfl_up(s, off, 64);
      if (lane >= off) s += y;
    }
    wsum[lane] = s;
  }
  __syncthreads();
  int incl = x + ((w == 0) ? 0 : wsum[w - 1]);
  if (i < NN) row_ptr[i + 1] = incl;
  if (t == 1023) bsum[blockIdx.x] = incl;
}

// ---------- phase 2: single-wave exclusive scan of block sums ----------
__global__ __launch_bounds__(64) void k_scan2(int* __restrict__ bsum) {
  const int t = threadIdx.x;
  int x = (t < SCAN_NBLK) ? bsum[t] : 0;
#pragma unroll
  for (int off = 1; off < 64; off <<= 1) {
    int y = __shfl_up(x, off, 64);
    if (t >= off) x += y;
  }
  int ex = __shfl_up(x, 1, 64);
  if (t == 0) ex = 0;
  if (t < SCAN_NBLK) bsum[t] = ex;
}

// ---------- phase 3: add block offsets ----------
__global__ __launch_bounds__(256) void k_scan3(const int* __restrict__ bsum,
                                               int* __restrict__ row_ptr) {
  const int i = blockIdx.x * 256 + threadIdx.x;
  if (i == 0) row_ptr[0] = 0;
  if (i < NN) row_ptr[i + 1] += bsum[i >> 10];
}

// ---------- fill CSR payload: dst-sorted src + f16 e_attr ----------
__global__ __launch_bounds__(256) void k_fill(
    const int* __restrict__ edge, const float* __restrict__ eattr,
    const int* __restrict__ row_ptr, int* __restrict__ cursor,
    int* __restrict__ ssrc, _Float16* __restrict__ sea8) {
  int e = blockIdx.x * 256 + threadIdx.x;
  if (e >= NE) return;
  int s = edge[e], d = edge[NE + e];
  int idx = row_ptr[d] + atomicAdd(&cursor[d], 1);
  ssrc[idx] = s;
  half8 v;
#pragma unroll
  for (int j = 0; j < EA; ++j) v[j] = (_Float16)eattr[(size_t)e * EA + j];
  v[6] = (_Float16)0.f; v[7] = (_Float16)0.f;
  *(half8*)(sea8 + (size_t)idx * 8) = v;
}

// ---------- segment starts from sorted bbox_idx ----------
__global__ __launch_bounds__(256) void k_segstart(const int* __restrict__ bbox,
                                                  int* __restrict__ seg) {
  int i = blockIdx.x * 256 + threadIdx.x;
  if (i >= NN) return;
  int bc = bbox[i];
  int bp = (i == 0) ? -1 : bbox[i - 1];
  for (int j = bp + 1; j <= bc; ++j) seg[j] = i;
  if (i == NN - 1)
    for (int j = bc + 1; j <= NB; ++j) seg[j] = NN;
}

// ---------- head node transform (K=8), both streams via blockIdx.y ----------
__global__ __launch_bounds__(256) void k_node_pq(
    const float* __restrict__ X, int ldx, int K,
    const float* __restrict__ WN, const float* __restrict__ bN,
    const float* __restrict__ WS, const float* __restrict__ bS,
    _Float16* __restrict__ PQi, _Float16* __restrict__ Qi) {
  const int sel = blockIdx.y;
  const float* W = sel ? WS : WN;
  const float* bias = sel ? bS : bN;
  const int t = threadIdx.x, lane = t & 63, wv = t >> 6;
  const int nbase = blockIdx.x * 32 + wv * 8;
  const int c = lane * 2;
  const float2 bv = *(const float2*)(bias + c);
  float2 pacc[8], qacc[8];
#pragma unroll
  for (int u = 0; u < 8; ++u) { pacc[u] = bv; qacc[u] = make_float2(0.f, 0.f); }
  const int xrow = min(nbase + (lane >> 3), NN - 1);
  const int xk = lane & 7;
  for (int k0 = 0; k0 < K; k0 += 8) {
    const float xv = X[(size_t)xrow * ldx + k0 + xk];
#pragma unroll
    for (int j = 0; j < 8; ++j) {
      const float2 w1 = *(const float2*)(W + (size_t)(k0 + j) * CH + c);
      const float2 w2 = *(const float2*)(W + (size_t)(K + k0 + j) * CH + c);
      const float2 wd = {w1.x - w2.x, w1.y - w2.y};
#pragma unroll
      for (int u = 0; u < 8; ++u) {
        const float xs = __shfl(xv, u * 8 + j, 64);
        pacc[u].x += xs * wd.x; pacc[u].y += xs * wd.y;
        qacc[u].x += xs * w2.x; qacc[u].y += xs * w2.y;
      }
    }
  }
#pragma unroll
  for (int u = 0; u < 8; ++u) {
    const int node = nbase + u;
    if (node < NN) {
      const size_t o = ((size_t)node * 64 + lane) * 4 + sel * 2;
      *(h2*)(PQi + o) = (h2){(_Float16)pacc[u].x, (_Float16)pacc[u].y};
      *(h2*)(Qi + o)  = (h2){(_Float16)qacc[u].x, (_Float16)qacc[u].y};
    }
  }
}

// ---------- pack [W1-W2 | W2] into f16 B-frags, both res-blocks (z) ----------
__global__ __launch_bounds__(64) void k_cvtWnpq(
    const float* __restrict__ WbAll, const float* __restrict__ WbsAll,
    _Float16* __restrict__ whN, _Float16* __restrict__ whS) {
  const int blk = blockIdx.z;
  const float* W = (blockIdx.y ? WbsAll : WbAll) + (size_t)blk * 262 * CH;
  _Float16* wh   = (blockIdx.y ? whS : whN) + (size_t)blk * 32768;
  const int c = blockIdx.x >> 4, tile = blockIdx.x & 15;
  const int L = threadIdx.x;
  const int n = tile * 16 + (L & 15);
  const int k0 = c * 32 + (L >> 4) * 8;
  half8 v;
#pragma unroll
  for (int j = 0; j < 8; ++j) {
    const int k = k0 + j;
    float val;
    if (n < CH) val = W[(size_t)k * CH + n] - W[(size_t)(CH + k) * CH + n];
    else        val = W[(size_t)(CH + k) * CH + (n - CH)];
    v[j] = (_Float16)val;
  }
  *(half8*)(wh + (((size_t)(c * 16 + tile)) * 64 + L) * 8) = v;
}

// ---------- residual node transform on matrix cores (both streams) ----------
// R7: X is f16 row-major [node][FUS] -> direct half8 A loads, no cvts.
__global__ __launch_bounds__(256) void k_npq_mfma(
    const _Float16* __restrict__ Xn, const _Float16* __restrict__ Xs, int ldx,
    const _Float16* __restrict__ whN, const _Float16* __restrict__ whS,
    const float* __restrict__ biasN, const float* __restrict__ biasS,
    _Float16* __restrict__ PQi, _Float16* __restrict__ Qi) {
  const int sel = blockIdx.y;
  const _Float16* X = sel ? Xs : Xn;
  const _Float16* wh = sel ? whS : whN;
  const float* bias = sel ? biasS : biasN;
  const int t = threadIdx.x, lane = t & 63, wv = t >> 6;
  const int nbase = blockIdx.x * 64;
  const int m = lane & 15, quad = lane >> 4;
  f32x4 acc[4][4];
#pragma unroll
  for (int i = 0; i < 4; ++i)
#pragma unroll
    for (int nt = 0; nt < 4; ++nt) acc[i][nt] = (f32x4){0.f, 0.f, 0.f, 0.f};
#pragma unroll
  for (int ks = 0; ks < 4; ++ks) {
    half8 b[4];
#pragma unroll
    for (int nt = 0; nt < 4; ++nt)
      b[nt] = *(const half8*)(wh + (((size_t)(ks * 16 + wv * 4 + nt)) * 64 + lane) * 8);
#pragma unroll
    for (int i = 0; i < 4; ++i) {
      const int row = min(nbase + i * 16 + m, NN - 1);
      const half8 a = *(const half8*)(X + (size_t)row * ldx + ks * 32 + quad * 8);
#pragma unroll
      for (int nt = 0; nt < 4; ++nt)
        acc[i][nt] = __builtin_amdgcn_mfma_f32_16x16x32_f16(a, b[nt], acc[i][nt],
                                                            0, 0, 0);
    }
  }
#pragma unroll
  for (int i = 0; i < 4; ++i)
#pragma unroll
    for (int nt = 0; nt < 4; ++nt) {
      const int col = wv * 64 + nt * 16 + m;
      const float bv = (col < CH) ? bias[col] : 0.f;
#pragma unroll
      for (int r = 0; r < 4; ++r) {
        const int row = nbase + i * 16 + quad * 4 + r;
        if (row < NN) {
          const float v = acc[i][nt][r] + bv;
          if (col < CH)
            PQi[((size_t)row * 64 + (col >> 1)) * 4 + sel * 2 + (col & 1)] =
                (_Float16)v;
          else {
            const int qc = col - CH;
            Qi[((size_t)row * 64 + (qc >> 1)) * 4 + sel * 2 + (qc & 1)] =
                (_Float16)v;
          }
        }
      }
    }
}

// ---------- fused dual-stream CSR conv ----------
// R2: packed-f16 edge math. R7: f16 feats + 8-deep gathers. R11: all edge
// metadata (src index + e_attr) is WAVE-UNIFORM (one node per wave, uniform
// loop counter) -> load via uniform scalar path instead of per-lane load +
// 4 shfl broadcasts per edge. Kills all ds_bpermute traffic and the per-lane
// 64-bit gather address math (gather = SGPR base + constant lane offset).
// Bit-identical math; only value transport changes.
__global__ __launch_bounds__(256) void k_conv2(
    const int* __restrict__ row_ptr, const int* __restrict__ ssrc,
    const _Float16* __restrict__ sea8,
    const _Float16* __restrict__ PQi, const _Float16* __restrict__ Qi,
    const float* __restrict__ Cn, const float* __restrict__ Cs,
    _Float16* __restrict__ feats, _Float16* __restrict__ sfeats,
    int cur, int prev) {
  const int t = threadIdx.x;
  const int lane = t & 63;
  const int node = blockIdx.x * 4 + (t >> 6);
  const int c = lane * 2;
  h2 cwnh[EA], cwsh[EA];
#pragma unroll
  for (int j = 0; j < EA; ++j) {
    const float2 a = *(const float2*)(Cn + j * CH + c);
    const float2 b = *(const float2*)(Cs + j * CH + c);
    cwnh[j] = (h2){(_Float16)a.x, (_Float16)a.y};
    cwsh[j] = (h2){(_Float16)b.x, (_Float16)b.y};
  }
  const int i0 = __builtin_amdgcn_readfirstlane(row_ptr[node]);
  const int i1 = __builtin_amdgcn_readfirstlane(row_ptr[node + 1]);
  const uint2 qv = *(const uint2*)(Qi + ((size_t)node * 64 + lane) * 4);
  const h2 qnh = *(const h2*)&qv.x;
  const h2 qsh = *(const h2*)&qv.y;
  const _Float16* pqL = PQi + (size_t)lane * 4;  // + s*256 per edge
  h2 anh = (h2){(_Float16)0.f, (_Float16)0.f};
  float as0 = 0.f, as1 = 0.f;
  const h2 zero = (h2){(_Float16)0.f, (_Float16)0.f};
#define COMP(PV, EAV)                                                      \
  {                                                                        \
    const h2 ea01 = *(const h2*)&EAV.x;                                    \
    const h2 ea23 = *(const h2*)&EAV.y;                                    \
    const h2 ea45 = *(const h2*)&EAV.z;                                    \
    h2 vn = *(const h2*)&PV.x + qnh;                                       \
    h2 vs = *(const h2*)&PV.y + qsh;                                       \
    h2 b;                                                                  \
    b = (h2){ea01[0], ea01[0]}; vn += b * cwnh[0]; vs += b * cwsh[0];      \
    b = (h2){ea01[1], ea01[1]}; vn += b * cwnh[1]; vs += b * cwsh[1];      \
    b = (h2){ea23[0], ea23[0]}; vn += b * cwnh[2]; vs += b * cwsh[2];      \
    b = (h2){ea23[1], ea23[1]}; vn += b * cwnh[3]; vs += b * cwsh[3];      \
    b = (h2){ea45[0], ea45[0]}; vn += b * cwnh[4]; vs += b * cwsh[4];      \
    b = (h2){ea45[1], ea45[1]}; vn += b * cwnh[5]; vs += b * cwsh[5];      \
    anh = __builtin_elementwise_max(anh, vn);                              \
    const h2 vsr = __builtin_elementwise_max(vs, zero);                    \
    as0 += (float)vsr[0]; as1 += (float)vsr[1];                            \
  }
  int j = i0;
  for (; j + 8 <= i1; j += 8) {
    // uniform scalar descriptors for 8 edges (SALU/k$ path, no shfls)
    const int s0 = ssrc[j],     s1 = ssrc[j + 1];
    const int s2 = ssrc[j + 2], s3 = ssrc[j + 3];
    const int s4 = ssrc[j + 4], s5 = ssrc[j + 5];
    const int s6 = ssrc[j + 6], s7 = ssrc[j + 7];
    const uint4 e0 = *(const uint4*)(sea8 + (size_t)(j    ) * 8);
    const uint4 e1 = *(const uint4*)(sea8 + (size_t)(j + 1) * 8);
    const uint4 e2 = *(const uint4*)(sea8 + (size_t)(j + 2) * 8);
    const uint4 e3 = *(const uint4*)(sea8 + (size_t)(j + 3) * 8);
    const uint4 e4 = *(const uint4*)(sea8 + (size_t)(j + 4) * 8);
    const uint4 e5 = *(const uint4*)(sea8 + (size_t)(j + 5) * 8);
    const uint4 e6 = *(const uint4*)(sea8 + (size_t)(j + 6) * 8);
    const uint4 e7 = *(const uint4*)(sea8 + (size_t)(j + 7) * 8);
    // 8 independent row gathers in flight before any compute
    const uint2 p0 = *(const uint2*)(pqL + (size_t)s0 * 256);
    const uint2 p1 = *(const uint2*)(pqL + (size_t)s1 * 256);
    const uint2 p2 = *(const uint2*)(pqL + (size_t)s2 * 256);
    const uint2 p3 = *(const uint2*)(pqL + (size_t)s3 * 256);
    const uint2 p4 = *(const uint2*)(pqL + (size_t)s4 * 256);
    const uint2 p5 = *(const uint2*)(pqL + (size_t)s5 * 256);
    const uint2 p6 = *(const uint2*)(pqL + (size_t)s6 * 256);
    const uint2 p7 = *(const uint2*)(pqL + (size_t)s7 * 256);
    COMP(p0, e0) COMP(p1, e1) COMP(p2, e2) COMP(p3, e3)
    COMP(p4, e4) COMP(p5, e5) COMP(p6, e6) COMP(p7, e7)
  }
  for (; j + 4 <= i1; j += 4) {
    const int s0 = ssrc[j],     s1 = ssrc[j + 1];
    const int s2 = ssrc[j + 2], s3 = ssrc[j + 3];
    const uint4 e0 = *(const uint4*)(sea8 + (size_t)(j    ) * 8);
    const uint4 e1 = *(const uint4*)(sea8 + (size_t)(j + 1) * 8);
    const uint4 e2 = *(const uint4*)(sea8 + (size_t)(j + 2) * 8);
    const uint4 e3 = *(const uint4*)(sea8 + (size_t)(j + 3) * 8);
    const uint2 p0 = *(const uint2*)(pqL + (size_t)s0 * 256);
    const uint2 p1 = *(const uint2*)(pqL + (size_t)s1 * 256);
    const uint2 p2 = *(const uint2*)(pqL + (size_t)s2 * 256);
    const uint2 p3 = *(const uint2*)(pqL + (size_t)s3 * 256);
    COMP(p0, e0) COMP(p1, e1) COMP(p2, e2) COMP(p3, e3)
  }
  for (; j < i1; ++j) {
    const int s0 = ssrc[j];
    const uint4 e0 = *(const uint4*)(sea8 + (size_t)j * 8);
    const uint2 p0 = *(const uint2*)(pqL + (size_t)s0 * 256);
    COMP(p0, e0)
  }
#undef COMP
  float an0 = (float)anh[0], an1 = (float)anh[1];
  const float inv = 1.f / fmaxf((float)(i1 - i0), 1.f);
  as0 *= inv; as1 *= inv;
  const size_t o = (size_t)node * FUS + (size_t)cur * CH + c;
  if (prev >= 0) {
    const size_t op = (size_t)node * FUS + (size_t)prev * CH + c;
    const h2 prn = *(const h2*)(feats + op);
    const h2 prs = *(const h2*)(sfeats + op);
    an0 += (float)prn[0]; an1 += (float)prn[1];
    as0 += (float)prs[0]; as1 += (float)prs[1];
  }
  *(h2*)(feats + o)  = (h2){(_Float16)an0, (_Float16)an1};
  *(h2*)(sfeats + o) = (h2){(_Float16)as0, (_Float16)as1};
}

// ---------- convert + pack W (KxN f32) into f16 B-fragment order ----------
template <int N, int NT>
__global__ __launch_bounds__(64) void k_cvtB(const float* __restrict__ W,
                                             _Float16* __restrict__ wh) {
  const int c = blockIdx.x / NT;
  const int tile = blockIdx.x % NT;
  const int L = threadIdx.x;
  const int n = tile * 16 + (L & 15);
  const int k0 = c * 32 + (L >> 4) * 8;
  half8 v;
#pragma unroll
  for (int j = 0; j < 8; ++j) v[j] = (_Float16)W[(size_t)(k0 + j) * N + n];
  *(half8*)(wh + (((size_t)(c * NT + tile)) * 64 + L) * 8) = v;
}

// ---------- dual-source variant (merged launch for W_f / W_fs) ----------
template <int N, int NT>
__global__ __launch_bounds__(64) void k_cvtB2(const float* __restrict__ WA,
                                              const float* __restrict__ WB,
                                              _Float16* __restrict__ whA,
                                              _Float16* __restrict__ whB) {
  const float* W = blockIdx.y ? WB : WA;
  _Float16* wh   = blockIdx.y ? whB : whA;
  const int c = blockIdx.x / NT;
  const int tile = blockIdx.x % NT;
  const int L = threadIdx.x;
  const int n = tile * 16 + (L & 15);
  const int k0 = c * 32 + (L >> 4) * 8;
  half8 v;
#pragma unroll
  for (int j = 0; j < 8; ++j) v[j] = (_Float16)W[(size_t)(k0 + j) * N + n];
  *(half8*)(wh + (((size_t)(c * NT + tile)) * 64 + L) * 8) = v;
}

// ---------- fusion GEMM + segment max ----
// R8 structure (measured 74-75us): LDS-staged A (wave wv stages frag i==wv),
// double-buffered, 2-deep prefetch, phase-carry run-merged atomicMax.
// Pool is a composite floor (~26us L2 + ~15-20us L3 A-stream + ~19us MFMA);
// occupancy/ILP/atomics/barriers all individually falsified (R1/R3/R8/R9).
__global__ __launch_bounds__(256, 6) void k_pool_mfma(
    const _Float16* __restrict__ feats16, const _Float16* __restrict__ wh,
    const int* __restrict__ bbox, const float* __restrict__ bf,
    float* __restrict__ pooled) {
  __shared__ float cl[32 * 132];
  __shared__ int s_bb[64];
  _Float16* abuf = (_Float16*)cl;  // 2 x 2048 halves (8KB), K-loop life only
  const int t = threadIdx.x, lane = t & 63, wv = t >> 6;
  const int fid = blockIdx.x;
  const int xcd = fid & 7, slot = fid >> 3;
  const int cg = slot & 7;
  const int rb = xcd * 98 + (slot >> 3);
  const int nbase = rb * 64;
  const int m = lane & 15, quad = lane >> 4;
  if (t < 64) s_bb[t] = bbox[min(nbase + t, NN - 1)];
  f32x4 acc[4][2];
#pragma unroll
  for (int i = 0; i < 4; ++i)
#pragma unroll
    for (int nt = 0; nt < 2; ++nt) acc[i][nt] = (f32x4){0.f, 0.f, 0.f, 0.f};
  // wave wv stages fragment i==wv of each K-chunk, from row-major feats16
  const _Float16* apc = feats16 + (size_t)(nbase + wv * 16 + m) * FUS + quad * 8;
  const _Float16* bp = wh + ((size_t)(cg * 8 + wv * 2) * 64 + lane) * 8;
  _Float16* wslot = abuf + wv * 512 + lane * 8;
  const _Float16* rbase = abuf + lane * 8;
  half8 b0 = *(const half8*)(bp);
  half8 b1 = *(const half8*)(bp + 512);
  half8 rA = *(const half8*)(apc);             // chunk 0 quarter
  *(half8*)(wslot) = rA;                       // -> buf0
  half8 rN = *(const half8*)(apc + 32);        // chunk 1 quarter
  __syncthreads();                             // buf0 ready (+ s_bb ordered)
#pragma unroll
  for (int ks = 0; ks < 12; ++ks) {
    const int cur = ks & 1;
    half8 nb0, nb1;
    if (ks < 11) {
      nb0 = *(const half8*)(bp + (size_t)(ks + 1) * 32768);
      nb1 = *(const half8*)(bp + (size_t)(ks + 1) * 32768 + 512);
    }
#pragma unroll
    for (int i = 0; i < 4; ++i) {
      const half8 a = *(const half8*)(rbase + cur * 2048 + i * 512);
      acc[i][0] = __builtin_amdgcn_mfma_f32_16x16x32_f16(a, b0, acc[i][0], 0, 0, 0);
      acc[i][1] = __builtin_amdgcn_mfma_f32_16x16x32_f16(a, b1, acc[i][1], 0, 0, 0);
    }
    if (ks < 11) {
      *(half8*)(wslot + (cur ^ 1) * 2048) = rN;   // stage chunk ks+1
      b0 = nb0; b1 = nb1;
    }
    if (ks < 10) rN = *(const half8*)(apc + (size_t)(ks + 2) * 32);
    __syncthreads();   // buf[cur^1] ready; all reads of buf[cur] done
  }
  const int col = t & 127, rh = t >> 7;
  const int gcol = cg * 128 + col;
  const float bias = bf[gcol];
  int curb = -1;
  float mx = 0.f;
#pragma unroll
  for (int p = 0; p < 2; ++p) {
    __syncthreads();  // p=1: phase-0 readers done with cl
#pragma unroll
    for (int ii = 0; ii < 2; ++ii)
#pragma unroll
      for (int nt = 0; nt < 2; ++nt) {
        const int scol = wv * 32 + nt * 16 + m;
#pragma unroll
        for (int r = 0; r < 4; ++r)
          cl[(ii * 16 + quad * 4 + r) * 132 + scol] = acc[p + 2 * ii][nt][r];
      }
    __syncthreads();
    for (int rr = 0; rr < 16; ++rr) {
      const int g = rh * 32 + p * 16 + rr;   // contiguous per-thread span
      const int node = nbase + g;
      if (node >= NN) break;
      const int bid = s_bb[g];
      const float v = fmaxf(cl[(rh * 16 + rr) * 132 + col] + bias, 0.f);
      if (bid != curb) {
        if (curb >= 0)
          atomicMax((unsigned*)(pooled + (size_t)curb * 1408 + gcol),
                    __float_as_uint(mx));
        curb = bid;
        mx = v;
      } else {
        mx = fmaxf(mx, v);
      }
    }
  }
  if (curb >= 0)
    atomicMax((unsigned*)(pooled + (size_t)curb * 1408 + gcol),
              __float_as_uint(mx));
}

// ---------- raw-feats bbox max + sfeats bbox mean (+ f16 sb copy) ----------
__global__ __launch_bounds__(256) void k_poolraw(
    const _Float16* __restrict__ feats, const _Float16* __restrict__ sfeats,
    const int* __restrict__ seg, float* __restrict__ pooled,
    float* __restrict__ sb, _Float16* __restrict__ sbH) {
  const int b = blockIdx.x, t = threadIdx.x;
  if (t >= 192) return;
  const int c2 = t * 2;
  const int n0 = __builtin_amdgcn_readfirstlane(seg[b]);
  const int n1 = __builtin_amdgcn_readfirstlane(seg[b + 1]);
  float2 fmx = {0.f, 0.f}, ss = {0.f, 0.f};
  for (int n = n0; n < n1; ++n) {
    const h2 f2 = *(const h2*)(feats + (size_t)n * FUS + c2);
    fmx.x = fmaxf(fmx.x, (float)f2[0]); fmx.y = fmaxf(fmx.y, (float)f2[1]);
    const h2 s2 = *(const h2*)(sfeats + (size_t)n * FUS + c2);
    ss.x += (float)s2[0]; ss.y += (float)s2[1];
  }
  *(float2*)(pooled + (size_t)b * 1408 + 1024 + c2) = fmx;
  const float inv = 1.f / fmaxf((float)(n1 - n0), 1.f);
  float2 o = {ss.x * inv, ss.y * inv};
  *(float2*)(sb + (size_t)b * FUS + c2) = o;
  *(h2*)(sbH + (size_t)b * FUS + c2) = (h2){(_Float16)o.x, (_Float16)o.y};
}

// ---------- fusion_super = relu(sbH @ WfsH + bfs) on matrix cores ----------
__global__ __launch_bounds__(256) void k_fsup_mfma(
    const _Float16* __restrict__ sbH, const _Float16* __restrict__ wh,
    const float* __restrict__ bfs, float* __restrict__ fs) {
  const int t = threadIdx.x, lane = t & 63, wv = t >> 6;
  const int nbase = blockIdx.x * 64;
  const int cg = blockIdx.y;
  const int m = lane & 15, quad = lane >> 4;
  f32x4 acc[4][2];
#pragma unroll
  for (int i = 0; i < 4; ++i)
#pragma unroll
    for (int nt = 0; nt < 2; ++nt) acc[i][nt] = (f32x4){0.f, 0.f, 0.f, 0.f};
  const _Float16* ap = sbH + (size_t)(nbase + m) * FUS + quad * 8;
  const _Float16* bp = wh + ((size_t)(cg * 8 + wv * 2) * 64 + lane) * 8;
#pragma unroll
  for (int ks = 0; ks < 12; ++ks) {
    const half8 b0 = *(const half8*)(bp + (size_t)ks * 32768);
    const half8 b1v = *(const half8*)(bp + (size_t)ks * 32768 + 512);
#pragma unroll
    for (int i = 0; i < 4; ++i) {
      const half8 a = *(const half8*)(ap + (size_t)(i * 16) * FUS + ks * 32);
      acc[i][0] = __builtin_amdgcn_mfma_f32_16x16x32_f16(a, b0, acc[i][0], 0, 0, 0);
      acc[i][1] = __builtin_amdgcn_mfma_f32_16x16x32_f16(a, b1v, acc[i][1], 0, 0, 0);
    }
  }
#pragma unroll
  for (int i = 0; i < 4; ++i)
#pragma unroll
    for (int nt = 0; nt < 2; ++nt) {
      const int gcol = cg * 128 + wv * 32 + nt * 16 + m;
      const float bias = bfs[gcol];
#pragma unroll
      for (int r = 0; r < 4; ++r) {
        const int row = nbase + i * 16 + quad * 4 + r;
        if (row < NB)
          fs[(size_t)row * 1024 + gcol] = fmaxf(acc[i][nt][r] + bias, 0.f);
      }
    }
}

// ---------- concat [pooled | fsup | sb] -> f16 bbH[NB_PAD][K1], zero-padded ----
__global__ __launch_bounds__(256) void k_cvt_cat(
    const float* __restrict__ pooled, const float* __restrict__ fsup,
    const float* __restrict__ sb, _Float16* __restrict__ bbH) {
  const size_t off = ((size_t)blockIdx.x * 256 + threadIdx.x) * 8;
  const int row = (int)(off / K1);
  const int col = (int)(off - (size_t)row * K1);
  half8 v;
  if (row < NB) {
    const float* src;
    if (col < 1408)      src = pooled + (size_t)row * 1408 + col;
    else if (col < 2432) src = fsup + (size_t)row * 1024 + (col - 1408);
    else                 src = sb + (size_t)row * FUS + (col - 2432);
    const float4 f0 = *(const float4*)src;
    const float4 f1 = *(const float4*)(src + 4);
    v[0] = (_Float16)f0.x; v[1] = (_Float16)f0.y;
    v[2] = (_Float16)f0.z; v[3] = (_Float16)f0.w;
    v[4] = (_Float16)f1.x; v[5] = (_Float16)f1.y;
    v[6] = (_Float16)f1.z; v[7] = (_Float16)f1.w;
  } else {
#pragma unroll
    for (int j = 0; j < 8; ++j) v[j] = (_Float16)0.f;
  }
  *(half8*)(bbH + off) = v;
}

// ---------- h1 = relu(bbH @ W1 + b1) on matrix cores ----------
// R10: cols split 8x64 (grid 32x8 = 256 blocks) -- full-GPU parallelism.
__global__ __launch_bounds__(256) void k_mlp1_mfma(
    const _Float16* __restrict__ bbH, const _Float16* __restrict__ wh,
    const float* __restrict__ b1, float* __restrict__ h1) {
  const int t = threadIdx.x, lane = t & 63, wv = t >> 6;
  const int nbase = blockIdx.x * 64;
  const int cg = blockIdx.y;           // 8 groups of 64 cols
  const int m = lane & 15, quad = lane >> 4;
  f32x4 acc[4];
#pragma unroll
  for (int i = 0; i < 4; ++i) acc[i] = (f32x4){0.f, 0.f, 0.f, 0.f};
  const _Float16* ap = bbH + (size_t)(nbase + m) * K1 + quad * 8;
  const _Float16* bp = wh + ((size_t)(cg * 4 + wv) * 64 + lane) * 8;
#pragma unroll 4
  for (int ks = 0; ks < 88; ++ks) {
    const half8 b0 = *(const half8*)(bp + (size_t)ks * 16384);
#pragma unroll
    for (int i = 0; i < 4; ++i) {
      const half8 a = *(const half8*)(ap + (size_t)(i * 16) * K1 + ks * 32);
      acc[i] = __builtin_amdgcn_mfma_f32_16x16x32_f16(a, b0, acc[i], 0, 0, 0);
    }
  }
#pragma unroll
  for (int i = 0; i < 4; ++i) {
    const int gcol = cg * 64 + wv * 16 + m;
    const float bias = b1[gcol];
#pragma unroll
    for (int r = 0; r < 4; ++r) {
      const int row = nbase + i * 16 + quad * 4 + r;
      if (row < NB)
        h1[(size_t)row * 512 + gcol] = fmaxf(acc[i][r] + bias, 0.f);
    }
  }
}

// ---------- h2 = relu(h1 @ W2 + b2) ----------
__global__ __launch_bounds__(256) void k_mlp2(
    const float* __restrict__ h1, const float* __restrict__ W2,
    const float* __restrict__ b2, float* __restrict__ h2o) {
  const int r0 = blockIdx.x * 8, t = threadIdx.x;
  float acc[8];
#pragma unroll
  for (int u = 0; u < 8; ++u) acc[u] = 0.f;
  for (int k = 0; k < 512; ++k) {
    float w = W2[(size_t)k * 256 + t];
#pragma unroll
    for (int u = 0; u < 8; ++u) acc[u] += h1[(size_t)(r0 + u) * 512 + k] * w;
  }
  float bv = b2[t];
#pragma unroll
  for (int u = 0; u < 8; ++u)
    h2o[(size_t)(r0 + u) * 256 + t] = fmaxf(acc[u] + bv, 0.f);
}

// ---------- logits = h2 @ W3 + b3 ----------
__global__ __launch_bounds__(256) void k_mlp3(
    const float* __restrict__ h2i, const float* __restrict__ W3,
    const float* __restrict__ b3, float* __restrict__ out) {
  const int r0 = blockIdx.x * 8, t = threadIdx.x;
  const int u = t >> 5, oc = t & 31;
  const float* x = h2i + (size_t)(r0 + u) * 256;
  float acc = 0.f;
  for (int k = 0; k < 256; ++k) acc += x[k] * W3[(size_t)k * 32 + oc];
  out[(size_t)(r0 + u) * 32 + oc] = acc + b3[oc];
}

extern "C" void kernel_launch(void* const* d_in, const int* in_sizes, int n_in,
                              void* d_out, int out_size, void* d_ws, size_t ws_size,
                              hipStream_t stream) {
  const float* x     = (const float*)d_in[0];
  const float* eattr = (const float*)d_in[1];
  const float* W_h   = (const float*)d_in[2];
  const float* b_h   = (const float*)d_in[3];
  const float* Ws_h  = (const float*)d_in[4];
  const float* bs_h  = (const float*)d_in[5];
  const float* Wb    = (const float*)d_in[6];
  const float* bb    = (const float*)d_in[7];
  const float* Wbs   = (const float*)d_in[8];
  const float* bbs   = (const float*)d_in[9];
  const float* W_f   = (const float*)d_in[10];
  const float* b_f   = (const float*)d_in[11];
  const float* W_fs  = (const float*)d_in[12];
  const float* b_fs  = (const float*)d_in[13];
  const float* W1    = (const float*)d_in[14];
  const float* b1    = (const float*)d_in[15];
  const float* W2    = (const float*)d_in[16];
  const float* b2    = (const float*)d_in[17];
  const float* W3    = (const float*)d_in[18];
  const float* b3    = (const float*)d_in[19];
  const int*   edge  = (const int*)d_in[20];
  const int*   bbox  = (const int*)d_in[21];
  float* out = (float*)d_out;

  // ---- workspace layout (~150 MB; budget >= 233 MB) ----
  _Float16* feats  = (_Float16*)d_ws;                 // [NN_PAD][FUS] f16
  _Float16* sfeats = feats + (size_t)NN_PAD * FUS;    // [NN_PAD][FUS] f16
  float* PQ = (float*)(sfeats + (size_t)NN_PAD * FUS); // 12.8M floats
  _Float16* PQi = (_Float16*)PQ;
  _Float16* Qi  = PQi + (size_t)NN * 256;
  // overlays inside PQ (live only AFTER the last k_conv2):
  float* sb   = PQ;
  float* fsup = sb + (size_t)NB * FUS;
  float* h1   = fsup + (size_t)NB * 1024;
  float* h2b  = h1 + (size_t)NB * 512;
  _Float16* bbH = (_Float16*)(h2b + (size_t)NB * 256);
  _Float16* W1H = bbH + (size_t)NB_PAD * K1;          // ends ~31.9MB
  _Float16* WfH = (_Float16*)PQ + (size_t)784 * 12 * 2048;  // at 38.5MB
  float* pooled = (float*)(WfH + (size_t)FUS * 1024);
  // CSR payload + misc after PQ region:
  _Float16* sea8 = (_Float16*)(PQ + (size_t)2 * NN * CH);
  int* ssrc    = (int*)(sea8 + (size_t)NE * 8);
  int* row_ptr = ssrc + NE;
  int* deg     = row_ptr + NN + 1;
  int* cursor  = deg + NN;
  int* seg     = cursor + NN;
  _Float16* WcatN = (_Float16*)(seg + NB + 1);        // 2 blocks x 128x256
  _Float16* WcatS = WcatN + (size_t)2 * 128 * 256;
  int* bsum = (int*)(WcatS + (size_t)2 * 128 * 256);
  _Float16* sbH = (_Float16*)(((uintptr_t)(bsum + SCAN_NBLK) + 127) &
                              ~(uintptr_t)127);       // [NB_PAD][FUS] f16
  _Float16* WfsH = sbH + (size_t)NB_PAD * FUS;        // 384x1024 B-frags

  hipMemsetAsync(deg, 0, 2 * NN * sizeof(int), stream);  // deg + cursor
  // zero the feats16 pad rows (read by pool_mfma staging)
  hipMemsetAsync(feats + (size_t)NN * FUS, 0,
                 (size_t)(NN_PAD - NN) * FUS * sizeof(_Float16), stream);

  // ---- CSR build (dst-sorted payload, parallel scan) + bbox segments ----
  k_deg<<<(NE + 255) / 256, 256, 0, stream>>>(edge, deg);
  k_scan1<<<SCAN_NBLK, 1024, 0, stream>>>(deg, row_ptr, bsum);
  k_scan2<<<1, 64, 0, stream>>>(bsum);
  k_scan3<<<(NN + 255) / 256, 256, 0, stream>>>(bsum, row_ptr);
  k_fill<<<(NE + 255) / 256, 256, 0, stream>>>(edge, eattr, row_ptr, cursor,
                                               ssrc, sea8);
  k_segstart<<<(NN + 255) / 256, 256, 0, stream>>>(bbox, seg);

  const int npq_grid = (NN + 31) / 32;

  // ---- conv 0 (head): both streams in one launch (blockIdx.y = sel) ----
  k_node_pq<<<dim3(npq_grid, 2), 256, 0, stream>>>(x, INCH, INCH, W_h, b_h,
                                                   Ws_h, bs_h, PQi, Qi);
  k_conv2<<<NN / 4, 256, 0, stream>>>(row_ptr, ssrc, sea8, PQi, Qi,
                                      W_h + 2 * INCH * CH, Ws_h + 2 * INCH * CH,
                                      feats, sfeats, 0, -1);

  // ---- residual blocks (K=128): weight prep hoisted, both blocks ----
  k_cvtWnpq<<<dim3(64, 2, 2), 64, 0, stream>>>(Wb, Wbs, WcatN, WcatS);
  for (int i = 0; i < 2; ++i) {
    const float* Wi  = Wb  + (size_t)i * 262 * CH;
    const float* bi  = bb  + (size_t)i * CH;
    const float* Wsi = Wbs + (size_t)i * 262 * CH;
    const float* bsi = bbs + (size_t)i * CH;
    k_npq_mfma<<<dim3((NN + 63) / 64, 2), 256, 0, stream>>>(
        feats + i * CH, sfeats + i * CH, FUS, WcatN + (size_t)i * 32768,
        WcatS + (size_t)i * 32768, bi, bsi, PQi, Qi);
    k_conv2<<<NN / 4, 256, 0, stream>>>(row_ptr, ssrc, sea8, PQi, Qi,
                                        Wi + 2 * CH * CH, Wsi + 2 * CH * CH,
                                        feats, sfeats, i + 1, i);
  }

  // ---- pooling: MFMA GEMM direct from feats16 + phase-carry atomicMax ----
  k_cvtB2<1024, 64><<<dim3(12 * 64, 2), 64, 0, stream>>>(W_f, W_fs, WfH, WfsH);
  hipMemsetAsync(pooled, 0, (size_t)NB * 1408 * sizeof(float), stream);
  k_pool_mfma<<<784 * 8, 256, 0, stream>>>(feats, WfH, bbox, b_f, pooled);
  k_poolraw<<<NB, 256, 0, stream>>>(feats, sfeats, seg, pooled, sb, sbH);
  k_fsup_mfma<<<dim3(NB_PAD / 64, 8), 256, 0, stream>>>(sbH, WfsH, b_fs, fsup);

  // ---- head MLP: concat->f16, W1->f16 frag, MFMA GEMM, then small MLPs ----
  k_cvt_cat<<<(int)(((size_t)NB_PAD * K1 / 8) / 256), 256, 0, stream>>>(
      pooled, fsup, sb, bbH);
  k_cvtB<512, 32><<<88 * 32, 64, 0, stream>>>(W1, W1H);
  k_mlp1_mfma<<<dim3(NB_PAD / 64, 8), 256, 0, stream>>>(bbH, W1H, b1, h1);
  k_mlp2<<<NB / 8, 256, 0, stream>>>(h1, W2, b2, h2b);
  k_mlp3<<<NB / 8, 256, 0, stream>>>(h2b, W3, b3, out);
}